// Round 1
// baseline (5818.816 us; speedup 1.0000x reference)
//
#include <hip/hip_runtime.h>
#include <hip/hip_bf16.h>

#define B_SZ 2
#define S_SZ 2048
#define DIM_SZ 3072
#define H_SZ 24
#define D_SZ 128
#define EPS_LN 1e-6f

// ---------------------------------------------------------------------------
// Generic fp32 GEMM: C[M,N] = A[M,K] @ B[K,N].  Tiles 128x128, BK=16.
// 256 threads, each computes 8x8 (rows ty*4+i and 64+ty*4+i, cols tx*4+j and
// 64+tx*4+j).  Requires M%128==0, N%128==0, K%16==0 (true for all our shapes).
// ---------------------------------------------------------------------------
__global__ __launch_bounds__(256) void gemm_f32(const float* __restrict__ A,
                                                const float* __restrict__ Bm,
                                                float* __restrict__ C,
                                                int M, int N, int K) {
  __shared__ float As[16][132];  // As[k][m], padded
  __shared__ float Bs[16][132];  // Bs[k][n], padded

  const int tid = threadIdx.x;
  const int tx = tid & 15;
  const int ty = tid >> 4;
  const int row0 = blockIdx.y * 128;
  const int col0 = blockIdx.x * 128;

  float acc[8][8];
#pragma unroll
  for (int i = 0; i < 8; ++i)
#pragma unroll
    for (int j = 0; j < 8; ++j) acc[i][j] = 0.f;

  for (int k0 = 0; k0 < K; k0 += 16) {
    // ---- load A tile: 128 rows x 16 k.  thread: m=tid>>1, k8=(tid&1)*8
    {
      const int m = tid >> 1;
      const int k8 = (tid & 1) * 8;
      const float* ap = A + (size_t)(row0 + m) * K + k0 + k8;
      const float4 x = *(const float4*)ap;
      const float4 y = *(const float4*)(ap + 4);
      As[k8 + 0][m] = x.x; As[k8 + 1][m] = x.y;
      As[k8 + 2][m] = x.z; As[k8 + 3][m] = x.w;
      As[k8 + 4][m] = y.x; As[k8 + 5][m] = y.y;
      As[k8 + 6][m] = y.z; As[k8 + 7][m] = y.w;
    }
    // ---- load B tile: 16 k x 128 cols. thread: k=tid>>4, n8=(tid&15)*8
    {
      const int kb = tid >> 4;
      const int n8 = (tid & 15) * 8;
      const float* bp = Bm + (size_t)(k0 + kb) * N + col0 + n8;
      *(float4*)&Bs[kb][n8] = *(const float4*)bp;
      *(float4*)&Bs[kb][n8 + 4] = *(const float4*)(bp + 4);
    }
    __syncthreads();

#pragma unroll
    for (int kk = 0; kk < 16; ++kk) {
      const float4 a0 = *(const float4*)&As[kk][ty * 4];
      const float4 a1 = *(const float4*)&As[kk][64 + ty * 4];
      const float4 b0 = *(const float4*)&Bs[kk][tx * 4];
      const float4 b1 = *(const float4*)&Bs[kk][64 + tx * 4];
      const float av[8] = {a0.x, a0.y, a0.z, a0.w, a1.x, a1.y, a1.z, a1.w};
      const float bv[8] = {b0.x, b0.y, b0.z, b0.w, b1.x, b1.y, b1.z, b1.w};
#pragma unroll
      for (int i = 0; i < 8; ++i)
#pragma unroll
        for (int j = 0; j < 8; ++j) acc[i][j] += av[i] * bv[j];
    }
    __syncthreads();
  }

#pragma unroll
  for (int i = 0; i < 8; ++i) {
    const int r = row0 + ((i < 4) ? (ty * 4 + i) : (64 + ty * 4 + (i - 4)));
    float4 c0, c1;
    c0.x = acc[i][0]; c0.y = acc[i][1]; c0.z = acc[i][2]; c0.w = acc[i][3];
    c1.x = acc[i][4]; c1.y = acc[i][5]; c1.z = acc[i][6]; c1.w = acc[i][7];
    *(float4*)(C + (size_t)r * N + col0 + tx * 4) = c0;
    *(float4*)(C + (size_t)r * N + col0 + 64 + tx * 4) = c1;
  }
}

// ---------------------------------------------------------------------------
// Fused per-head fp32 LayerNorm (over D=128) + interleaved RoPE.
// One 128-thread block per (b,s,head) row.  heads = H for q, 1 for k.
// out[2i]   = y[2i]*cos(ang[s,i]) - y[2i+1]*sin(ang[s,i])
// out[2i+1] = y[2i]*sin(ang[s,i]) + y[2i+1]*cos(ang[s,i])
// freqs_cos/sin are repeat(...,2) so fc[s*128+d] == cos(ang[s,d>>1]).
// ---------------------------------------------------------------------------
__global__ __launch_bounds__(128) void ln_rope(const float* __restrict__ X,
                                               float* __restrict__ Y,
                                               const float* __restrict__ g,
                                               const float* __restrict__ be,
                                               const float* __restrict__ fc,
                                               const float* __restrict__ fs,
                                               int heads) {
  __shared__ float red[4];
  const int row = blockIdx.x;
  const int d = threadIdx.x;
  const int s = (row / heads) % S_SZ;

  const float x = X[(size_t)row * D_SZ + d];
  float v1 = x, v2 = x * x;
#pragma unroll
  for (int off = 1; off < 64; off <<= 1) {
    v1 += __shfl_xor(v1, off);
    v2 += __shfl_xor(v2, off);
  }
  const int w = d >> 6;
  if ((d & 63) == 0) { red[w * 2] = v1; red[w * 2 + 1] = v2; }
  __syncthreads();
  const float sum = red[0] + red[2];
  const float sumsq = red[1] + red[3];
  const float mean = sum * (1.f / 128.f);
  const float var = sumsq * (1.f / 128.f) - mean * mean;
  const float inv = rsqrtf(var + EPS_LN);
  const float y = (x - mean) * inv * g[d] + be[d];
  const float yp = __shfl_xor(y, 1);
  const float c = fc[(size_t)s * D_SZ + d];
  const float sn = fs[(size_t)s * D_SZ + d];
  const float o = (d & 1) ? (yp * sn + y * c) : (y * c - yp * sn);
  Y[(size_t)row * D_SZ + d] = o;
}

// ---------------------------------------------------------------------------
// Flash-style fp32 MQA attention.  HKV=1: K,V are (B,S,D).
// Block = 256 threads handles one (b,h) and 16 q-rows; iterates 32-key tiles
// with online softmax.  Thread (r=tid>>4, tx=tid&15) owns q-row r and output
// cols {tx*4..tx*4+3} u {64+tx*4..64+tx*4+3}.
// ---------------------------------------------------------------------------
__global__ __launch_bounds__(256) void attn_f32(const float* __restrict__ Q,
                                                const float* __restrict__ Kb,
                                                const float* __restrict__ Vb,
                                                float* __restrict__ O) {
  __shared__ float Qs[16][132];
  __shared__ float Ks[32][132];
  __shared__ float Vs[32][132];
  __shared__ float Ss[16][33];

  const int tid = threadIdx.x;
  const int qt = blockIdx.x & 127;              // S/16 = 128 q-tiles
  const int h = (blockIdx.x >> 7) % H_SZ;
  const int b = blockIdx.x / (128 * H_SZ);
  const int r = tid >> 4;
  const int tx = tid & 15;

  // stage Q tile (16 rows x 128)
  {
    const int d0 = tx * 8;
    const float* qp =
        Q + ((size_t)(b * S_SZ + qt * 16 + r) * H_SZ + h) * D_SZ + d0;
    *(float4*)&Qs[r][d0] = *(const float4*)qp;
    *(float4*)&Qs[r][d0 + 4] = *(const float4*)(qp + 4);
  }

  float m_run = -1e30f, l_run = 0.f;
  float ac[8];
#pragma unroll
  for (int j = 0; j < 8; ++j) ac[j] = 0.f;
  const float scale = 0.08838834764831845f;  // 1/sqrt(128)

  for (int kt = 0; kt < S_SZ / 32; ++kt) {
    __syncthreads();  // previous iter's reads of Ks/Vs/Ss done
    // stage K,V tile (32 rows x 128)
    {
      const int rr = tid >> 3;
      const int d0 = (tid & 7) * 16;
      const float* kp = Kb + (size_t)(b * S_SZ + kt * 32 + rr) * D_SZ + d0;
      const float* vp = Vb + (size_t)(b * S_SZ + kt * 32 + rr) * D_SZ + d0;
#pragma unroll
      for (int j = 0; j < 16; j += 4) {
        *(float4*)&Ks[rr][d0 + j] = *(const float4*)(kp + j);
        *(float4*)&Vs[rr][d0 + j] = *(const float4*)(vp + j);
      }
    }
    __syncthreads();

    // scores for keys tx and tx+16 of this tile
    {
      float s0 = 0.f, s1 = 0.f;
      const float4* qv = (const float4*)&Qs[r][0];
      const float4* k0v = (const float4*)&Ks[tx][0];
      const float4* k1v = (const float4*)&Ks[tx + 16][0];
#pragma unroll
      for (int j = 0; j < 32; ++j) {
        const float4 q4 = qv[j];
        const float4 x4 = k0v[j];
        const float4 y4 = k1v[j];
        s0 += q4.x * x4.x + q4.y * x4.y + q4.z * x4.z + q4.w * x4.w;
        s1 += q4.x * y4.x + q4.y * y4.y + q4.z * y4.z + q4.w * y4.w;
      }
      Ss[r][tx] = s0 * scale;
      Ss[r][tx + 16] = s1 * scale;
    }
    __syncthreads();

    // online softmax + PV for this tile
    {
      float mloc = -1e30f;
#pragma unroll
      for (int k = 0; k < 32; ++k) mloc = fmaxf(mloc, Ss[r][k]);
      const float m_new = fmaxf(m_run, mloc);
      const float corr = __expf(m_run - m_new);
      m_run = m_new;
      l_run *= corr;
#pragma unroll
      for (int j = 0; j < 8; ++j) ac[j] *= corr;
#pragma unroll
      for (int k = 0; k < 32; ++k) {
        const float p = __expf(Ss[r][k] - m_new);
        l_run += p;
        const float4 v0 = *(const float4*)&Vs[k][tx * 4];
        const float4 v1 = *(const float4*)&Vs[k][64 + tx * 4];
        ac[0] += p * v0.x; ac[1] += p * v0.y;
        ac[2] += p * v0.z; ac[3] += p * v0.w;
        ac[4] += p * v1.x; ac[5] += p * v1.y;
        ac[6] += p * v1.z; ac[7] += p * v1.w;
      }
    }
  }

  const float inv = 1.f / l_run;
  float* op = O + ((size_t)(b * S_SZ + qt * 16 + r) * H_SZ + h) * D_SZ;
  float4 o0, o1;
  o0.x = ac[0] * inv; o0.y = ac[1] * inv; o0.z = ac[2] * inv; o0.w = ac[3] * inv;
  o1.x = ac[4] * inv; o1.y = ac[5] * inv; o1.z = ac[6] * inv; o1.w = ac[7] * inv;
  *(float4*)(op + tx * 4) = o0;
  *(float4*)(op + 64 + tx * 4) = o1;
}

// ---------------------------------------------------------------------------
extern "C" void kernel_launch(void* const* d_in, const int* in_sizes, int n_in,
                              void* d_out, int out_size, void* d_ws,
                              size_t ws_size, hipStream_t stream) {
  const float* hidden = (const float*)d_in[0];
  const float* fcos = (const float*)d_in[1];
  const float* fsin = (const float*)d_in[2];
  const float* w_q = (const float*)d_in[3];
  const float* w_k = (const float*)d_in[4];
  const float* w_v = (const float*)d_in[5];
  const float* w_o = (const float*)d_in[6];
  const float* ln_q_w = (const float*)d_in[7];
  const float* ln_q_b = (const float*)d_in[8];
  const float* ln_k_w = (const float*)d_in[9];
  const float* ln_k_b = (const float*)d_in[10];
  float* out = (float*)d_out;

  const int M = B_SZ * S_SZ;  // 4096

  // d_out doubles as the Q buffer (fully consumed by attention before the
  // final GEMM overwrites it).  Workspace: attn_out + k + v  (~52 MB).
  float* q_buf = out;
  float* a_buf = (float*)d_ws;                       // M * H*D
  float* k_buf = a_buf + (size_t)M * H_SZ * D_SZ;    // M * D
  float* v_buf = k_buf + (size_t)M * D_SZ;           // M * D

  const dim3 blk(256);

  // QKV projections
  gemm_f32<<<dim3(DIM_SZ / 128, M / 128), blk, 0, stream>>>(hidden, w_q, q_buf,
                                                            M, DIM_SZ, DIM_SZ);
  gemm_f32<<<dim3(1, M / 128), blk, 0, stream>>>(hidden, w_k, k_buf, M, D_SZ,
                                                 DIM_SZ);
  gemm_f32<<<dim3(1, M / 128), blk, 0, stream>>>(hidden, w_v, v_buf, M, D_SZ,
                                                 DIM_SZ);

  // per-head LN + RoPE (in-place)
  ln_rope<<<M * H_SZ, 128, 0, stream>>>(q_buf, q_buf, ln_q_w, ln_q_b, fcos,
                                        fsin, H_SZ);
  ln_rope<<<M, 128, 0, stream>>>(k_buf, k_buf, ln_k_w, ln_k_b, fcos, fsin, 1);

  // attention (MQA, no mask)
  attn_f32<<<B_SZ * H_SZ * (S_SZ / 16), blk, 0, stream>>>(q_buf, k_buf, v_buf,
                                                          a_buf);

  // output projection
  gemm_f32<<<dim3(DIM_SZ / 128, M / 128), blk, 0, stream>>>(a_buf, w_o, out, M,
                                                            DIM_SZ, DIM_SZ);
}

// Round 2
// 3031.119 us; speedup vs baseline: 1.9197x; 1.9197x over previous
//
#include <hip/hip_runtime.h>
#include <hip/hip_bf16.h>

#define B_SZ 2
#define S_SZ 2048
#define DIM_SZ 3072
#define H_SZ 24
#define D_SZ 128
#define EPS_LN 1e-6f

typedef __attribute__((ext_vector_type(8))) short short8;
typedef __attribute__((ext_vector_type(4))) float f32x4;
typedef __attribute__((ext_vector_type(4))) unsigned int u32x4;

__device__ __forceinline__ unsigned short f2bf(float f) {
  union { float f; unsigned u; } x; x.f = f;
  unsigned r = x.u + 0x7fffu + ((x.u >> 16) & 1u);   // RNE
  return (unsigned short)(r >> 16);
}
__device__ __forceinline__ unsigned pack2(float a, float b) {
  return (unsigned)f2bf(a) | ((unsigned)f2bf(b) << 16);
}

// ---------------------------------------------------------------------------
// Generic fp32 GEMM: C[M,N] = A[M,K] @ B[K,N].  Tiles 128x128, BK=16.
// ---------------------------------------------------------------------------
__global__ __launch_bounds__(256) void gemm_f32(const float* __restrict__ A,
                                                const float* __restrict__ Bm,
                                                float* __restrict__ C,
                                                int M, int N, int K) {
  __shared__ float As[16][132];
  __shared__ float Bs[16][132];

  const int tid = threadIdx.x;
  const int tx = tid & 15;
  const int ty = tid >> 4;
  const int row0 = blockIdx.y * 128;
  const int col0 = blockIdx.x * 128;

  float acc[8][8];
#pragma unroll
  for (int i = 0; i < 8; ++i)
#pragma unroll
    for (int j = 0; j < 8; ++j) acc[i][j] = 0.f;

  for (int k0 = 0; k0 < K; k0 += 16) {
    {
      const int m = tid >> 1;
      const int k8 = (tid & 1) * 8;
      const float* ap = A + (size_t)(row0 + m) * K + k0 + k8;
      const float4 x = *(const float4*)ap;
      const float4 y = *(const float4*)(ap + 4);
      As[k8 + 0][m] = x.x; As[k8 + 1][m] = x.y;
      As[k8 + 2][m] = x.z; As[k8 + 3][m] = x.w;
      As[k8 + 4][m] = y.x; As[k8 + 5][m] = y.y;
      As[k8 + 6][m] = y.z; As[k8 + 7][m] = y.w;
    }
    {
      const int kb = tid >> 4;
      const int n8 = (tid & 15) * 8;
      const float* bp = Bm + (size_t)(k0 + kb) * N + col0 + n8;
      *(float4*)&Bs[kb][n8] = *(const float4*)bp;
      *(float4*)&Bs[kb][n8 + 4] = *(const float4*)(bp + 4);
    }
    __syncthreads();

#pragma unroll
    for (int kk = 0; kk < 16; ++kk) {
      const float4 a0 = *(const float4*)&As[kk][ty * 4];
      const float4 a1 = *(const float4*)&As[kk][64 + ty * 4];
      const float4 b0 = *(const float4*)&Bs[kk][tx * 4];
      const float4 b1 = *(const float4*)&Bs[kk][64 + tx * 4];
      const float av[8] = {a0.x, a0.y, a0.z, a0.w, a1.x, a1.y, a1.z, a1.w};
      const float bv[8] = {b0.x, b0.y, b0.z, b0.w, b1.x, b1.y, b1.z, b1.w};
#pragma unroll
      for (int i = 0; i < 8; ++i)
#pragma unroll
        for (int j = 0; j < 8; ++j) acc[i][j] += av[i] * bv[j];
    }
    __syncthreads();
  }

#pragma unroll
  for (int i = 0; i < 8; ++i) {
    const int r = row0 + ((i < 4) ? (ty * 4 + i) : (64 + ty * 4 + (i - 4)));
    float4 c0, c1;
    c0.x = acc[i][0]; c0.y = acc[i][1]; c0.z = acc[i][2]; c0.w = acc[i][3];
    c1.x = acc[i][4]; c1.y = acc[i][5]; c1.z = acc[i][6]; c1.w = acc[i][7];
    *(float4*)(C + (size_t)r * N + col0 + tx * 4) = c0;
    *(float4*)(C + (size_t)r * N + col0 + 64 + tx * 4) = c1;
  }
}

// ---------------------------------------------------------------------------
// Fused per-head fp32 LayerNorm (D=128) + interleaved RoPE, in place.
// ---------------------------------------------------------------------------
__global__ __launch_bounds__(128) void ln_rope(const float* __restrict__ X,
                                               float* __restrict__ Y,
                                               const float* __restrict__ g,
                                               const float* __restrict__ be,
                                               const float* __restrict__ fc,
                                               const float* __restrict__ fs,
                                               int heads) {
  __shared__ float red[4];
  const int row = blockIdx.x;
  const int d = threadIdx.x;
  const int s = (row / heads) % S_SZ;

  const float x = X[(size_t)row * D_SZ + d];
  float v1 = x, v2 = x * x;
#pragma unroll
  for (int off = 1; off < 64; off <<= 1) {
    v1 += __shfl_xor(v1, off);
    v2 += __shfl_xor(v2, off);
  }
  const int w = d >> 6;
  if ((d & 63) == 0) { red[w * 2] = v1; red[w * 2 + 1] = v2; }
  __syncthreads();
  const float sum = red[0] + red[2];
  const float sumsq = red[1] + red[3];
  const float mean = sum * (1.f / 128.f);
  const float var = sumsq * (1.f / 128.f) - mean * mean;
  const float inv = rsqrtf(var + EPS_LN);
  const float y = (x - mean) * inv * g[d] + be[d];
  const float yp = __shfl_xor(y, 1);
  const float c = fc[(size_t)s * D_SZ + d];
  const float sn = fs[(size_t)s * D_SZ + d];
  const float o = (d & 1) ? (yp * sn + y * c) : (y * c - yp * sn);
  Y[(size_t)row * D_SZ + d] = o;
}

// ---------------------------------------------------------------------------
// Flash-style bf16 MFMA MQA attention (HKV=1).
// Block = 256 threads (4 waves), handles (b, h, 64 q-rows).  Per 64-key tile:
// stage K[64][128] and V^T[128][64] bf16 in LDS (XOR swizzle byte^=((row&7)<<4)
// to kill the D=128 row-stride bank conflict), QK^T via 16x16x32 MFMA with Q
// fragments in registers (scale folded), online softmax in C-layout
// (col=lane&15, row=(lane>>4)*4+reg), P re-shaped to A-operand via a per-wave
// swizzled LDS buffer, PV via MFMA with V^T as the B operand.
// ---------------------------------------------------------------------------
__global__ __launch_bounds__(256) void attn_mfma(const float* __restrict__ Qf,
                                                 const float* __restrict__ Kf,
                                                 const float* __restrict__ Vf,
                                                 float* __restrict__ Of) {
  __shared__ unsigned short KsS[64 * 128];   // 16 KB
  __shared__ unsigned short VtS[128 * 64];   // 16 KB
  __shared__ unsigned short PsS[4][16 * 64]; //  8 KB (per-wave)

  const int tid = threadIdx.x;
  const int l = tid & 63;
  const int w = tid >> 6;
  const int l15 = l & 15;
  const int lg = l >> 4;

  const int qt = blockIdx.x & 31;            // 32 q-tiles of 64 rows
  const int h = (blockIdx.x >> 5) % H_SZ;
  const int b = blockIdx.x / (32 * H_SZ);

  char* KsB = (char*)KsS;
  char* VtB = (char*)VtS;
  char* PsB = (char*)&PsS[w][0];

  // ---- Q fragments (A operand), softmax scale folded in ----
  short8 qa[4];
  {
    const int qrow = qt * 64 + w * 16 + l15;
    const float* qp =
        Qf + (((size_t)(b * S_SZ + qrow)) * H_SZ + h) * D_SZ + lg * 8;
    const float sc = 0.08838834764831845f;  // 1/sqrt(128)
#pragma unroll
    for (int kt = 0; kt < 4; ++kt) {
      const float4 x = *(const float4*)(qp + kt * 32);
      const float4 y = *(const float4*)(qp + kt * 32 + 4);
      short8 q;
      q[0] = (short)f2bf(x.x * sc); q[1] = (short)f2bf(x.y * sc);
      q[2] = (short)f2bf(x.z * sc); q[3] = (short)f2bf(x.w * sc);
      q[4] = (short)f2bf(y.x * sc); q[5] = (short)f2bf(y.y * sc);
      q[6] = (short)f2bf(y.z * sc); q[7] = (short)f2bf(y.w * sc);
      qa[kt] = q;
    }
  }

  f32x4 oacc[8];
#pragma unroll
  for (int dt = 0; dt < 8; ++dt) oacc[dt] = (f32x4)0.f;
  float m_run[4] = {-1e30f, -1e30f, -1e30f, -1e30f};
  float l_run[4] = {0.f, 0.f, 0.f, 0.f};

  const int krow = tid >> 2;        // K stage: row 0..63
  const int kch = (tid & 3) * 32;   //          32-elem chunk
  const int vk0 = (tid & 31) * 2;   // V stage: key pair
  const int vdb = (tid >> 5) * 16;  //          16-d block

  for (int kv0 = 0; kv0 < S_SZ; kv0 += 64) {
    __syncthreads();  // all waves done reading previous tile
    // ---- stage K tile (fp32 -> bf16, swizzled) ----
    {
      const float* kp = Kf + ((size_t)(b * S_SZ + kv0 + krow)) * D_SZ + kch;
      const int xr = (krow & 7) << 4;
#pragma unroll
      for (int i = 0; i < 4; ++i) {
        const float4 x = *(const float4*)(kp + i * 8);
        const float4 y = *(const float4*)(kp + i * 8 + 4);
        u32x4 pk;
        pk[0] = pack2(x.x, x.y); pk[1] = pack2(x.z, x.w);
        pk[2] = pack2(y.x, y.y); pk[3] = pack2(y.z, y.w);
        *(u32x4*)(KsB + krow * 256 + ((kch * 2 + i * 16) ^ xr)) = pk;
      }
    }
    // ---- stage V tile transposed (fp32 -> bf16, swizzled) ----
    {
      const float* vp0 = Vf + ((size_t)(b * S_SZ + kv0 + vk0)) * D_SZ + vdb;
      const float* vp1 = vp0 + D_SZ;
#pragma unroll
      for (int i = 0; i < 4; ++i) {
        const float4 x0 = *(const float4*)(vp0 + i * 4);
        const float4 x1 = *(const float4*)(vp1 + i * 4);
        const int r0 = vdb + i * 4;
        *(unsigned*)(VtB + (r0 + 0) * 128 + ((vk0 * 2) ^ (((r0 + 0) & 7) << 4))) = pack2(x0.x, x1.x);
        *(unsigned*)(VtB + (r0 + 1) * 128 + ((vk0 * 2) ^ (((r0 + 1) & 7) << 4))) = pack2(x0.y, x1.y);
        *(unsigned*)(VtB + (r0 + 2) * 128 + ((vk0 * 2) ^ (((r0 + 2) & 7) << 4))) = pack2(x0.z, x1.z);
        *(unsigned*)(VtB + (r0 + 3) * 128 + ((vk0 * 2) ^ (((r0 + 3) & 7) << 4))) = pack2(x0.w, x1.w);
      }
    }
    __syncthreads();

    // ---- QK^T: 4 key-subtiles x 4 K-chunks ----
    f32x4 sacc[4];
#pragma unroll
    for (int c = 0; c < 4; ++c) sacc[c] = (f32x4)0.f;
#pragma unroll
    for (int c = 0; c < 4; ++c) {
      const int kr = c * 16 + l15;
      const int xr = (kr & 7) << 4;
#pragma unroll
      for (int kt = 0; kt < 4; ++kt) {
        const short8 kb =
            *(const short8*)(KsB + kr * 256 + ((kt * 64 + lg * 16) ^ xr));
        sacc[c] =
            __builtin_amdgcn_mfma_f32_16x16x32_bf16(qa[kt], kb, sacc[c], 0, 0, 0);
      }
    }

    // ---- online softmax (rows live in 16-lane groups) ----
    float mx[4], mnew[4], corr[4], psum[4];
#pragma unroll
    for (int r = 0; r < 4; ++r)
      mx[r] = fmaxf(fmaxf(sacc[0][r], sacc[1][r]),
                    fmaxf(sacc[2][r], sacc[3][r]));
#pragma unroll
    for (int off = 1; off < 16; off <<= 1)
#pragma unroll
      for (int r = 0; r < 4; ++r) mx[r] = fmaxf(mx[r], __shfl_xor(mx[r], off));
#pragma unroll
    for (int r = 0; r < 4; ++r) {
      mnew[r] = fmaxf(m_run[r], mx[r]);
      corr[r] = __expf(m_run[r] - mnew[r]);
      m_run[r] = mnew[r];
      psum[r] = 0.f;
    }
#pragma unroll
    for (int c = 0; c < 4; ++c) {
#pragma unroll
      for (int r = 0; r < 4; ++r) {
        const float p = __expf(sacc[c][r] - mnew[r]);
        psum[r] += p;
        const int row = lg * 4 + r;
        *(unsigned short*)(PsB + row * 128 +
                           (((c * 16 + l15) * 2) ^ ((row & 7) << 4))) = f2bf(p);
      }
    }
#pragma unroll
    for (int off = 1; off < 16; off <<= 1)
#pragma unroll
      for (int r = 0; r < 4; ++r) psum[r] += __shfl_xor(psum[r], off);
#pragma unroll
    for (int r = 0; r < 4; ++r) l_run[r] = l_run[r] * corr[r] + psum[r];
#pragma unroll
    for (int dt = 0; dt < 8; ++dt)
#pragma unroll
      for (int r = 0; r < 4; ++r) oacc[dt][r] *= corr[r];

    // ---- PV: out += P @ V  (A from per-wave P buffer, B from V^T) ----
#pragma unroll
    for (int kt2 = 0; kt2 < 2; ++kt2) {
      const short8 pa = *(const short8*)(
          PsB + l15 * 128 + ((kt2 * 64 + lg * 16) ^ ((l15 & 7) << 4)));
#pragma unroll
      for (int dt = 0; dt < 8; ++dt) {
        const int vr = dt * 16 + l15;
        const short8 vb = *(const short8*)(
            VtB + vr * 128 + ((kt2 * 64 + lg * 16) ^ ((vr & 7) << 4)));
        oacc[dt] =
            __builtin_amdgcn_mfma_f32_16x16x32_bf16(pa, vb, oacc[dt], 0, 0, 0);
      }
    }
  }

  // ---- epilogue: normalize and store fp32 (B,S,H,D) ----
  float inv[4];
#pragma unroll
  for (int r = 0; r < 4; ++r) inv[r] = 1.f / l_run[r];
  const size_t obase =
      (((size_t)(b * S_SZ + qt * 64 + w * 16)) * H_SZ + h) * D_SZ;
#pragma unroll
  for (int dt = 0; dt < 8; ++dt)
#pragma unroll
    for (int r = 0; r < 4; ++r)
      Of[obase + (size_t)(lg * 4 + r) * (H_SZ * D_SZ) + dt * 16 + l15] =
          oacc[dt][r] * inv[r];
}

// ---------------------------------------------------------------------------
extern "C" void kernel_launch(void* const* d_in, const int* in_sizes, int n_in,
                              void* d_out, int out_size, void* d_ws,
                              size_t ws_size, hipStream_t stream) {
  const float* hidden = (const float*)d_in[0];
  const float* fcos = (const float*)d_in[1];
  const float* fsin = (const float*)d_in[2];
  const float* w_q = (const float*)d_in[3];
  const float* w_k = (const float*)d_in[4];
  const float* w_v = (const float*)d_in[5];
  const float* w_o = (const float*)d_in[6];
  const float* ln_q_w = (const float*)d_in[7];
  const float* ln_q_b = (const float*)d_in[8];
  const float* ln_k_w = (const float*)d_in[9];
  const float* ln_k_b = (const float*)d_in[10];
  float* out = (float*)d_out;

  const int M = B_SZ * S_SZ;  // 4096

  float* q_buf = out;                                // M * H*D (fp32)
  float* a_buf = (float*)d_ws;                       // M * H*D
  float* k_buf = a_buf + (size_t)M * H_SZ * D_SZ;    // M * D
  float* v_buf = k_buf + (size_t)M * D_SZ;           // M * D

  const dim3 blk(256);

  gemm_f32<<<dim3(DIM_SZ / 128, M / 128), blk, 0, stream>>>(hidden, w_q, q_buf,
                                                            M, DIM_SZ, DIM_SZ);
  gemm_f32<<<dim3(1, M / 128), blk, 0, stream>>>(hidden, w_k, k_buf, M, D_SZ,
                                                 DIM_SZ);
  gemm_f32<<<dim3(1, M / 128), blk, 0, stream>>>(hidden, w_v, v_buf, M, D_SZ,
                                                 DIM_SZ);

  ln_rope<<<M * H_SZ, 128, 0, stream>>>(q_buf, q_buf, ln_q_w, ln_q_b, fcos,
                                        fsin, H_SZ);
  ln_rope<<<M, 128, 0, stream>>>(k_buf, k_buf, ln_k_w, ln_k_b, fcos, fsin, 1);

  attn_mfma<<<B_SZ * H_SZ * 32, blk, 0, stream>>>(q_buf, k_buf, v_buf, a_buf);

  gemm_f32<<<dim3(DIM_SZ / 128, M / 128), blk, 0, stream>>>(a_buf, w_o, out, M,
                                                            DIM_SZ, DIM_SZ);
}

// Round 3
// 644.329 us; speedup vs baseline: 9.0308x; 4.7043x over previous
//
#include <hip/hip_runtime.h>
#include <hip/hip_bf16.h>

#define B_SZ 2
#define S_SZ 2048
#define DIM_SZ 3072
#define H_SZ 24
#define D_SZ 128
#define EPS_LN 1e-6f

typedef __attribute__((ext_vector_type(8))) short short8;
typedef __attribute__((ext_vector_type(4))) float f32x4;
typedef __attribute__((ext_vector_type(4))) unsigned int u32x4;
typedef unsigned short u16;

__device__ __forceinline__ u16 f2bf(float f) {
  union { float f; unsigned u; } x; x.f = f;
  unsigned r = x.u + 0x7fffu + ((x.u >> 16) & 1u);  // RNE
  return (u16)(r >> 16);
}
__device__ __forceinline__ unsigned pack2(float a, float b) {
  return (unsigned)f2bf(a) | ((unsigned)f2bf(b) << 16);
}

// CK-proven idiom for async global->LDS (16B per lane).
typedef const __attribute__((address_space(1))) void* gas_ptr;
typedef __attribute__((address_space(3))) void* las_ptr;
__device__ __forceinline__ void gload_lds16(const void* g, void* l) {
  __builtin_amdgcn_global_load_lds(
      reinterpret_cast<gas_ptr>(reinterpret_cast<uintptr_t>(g)),
      reinterpret_cast<las_ptr>(reinterpret_cast<uintptr_t>(l)), 16, 0, 0);
}

// ---------------------------------------------------------------------------
// bf16 MFMA GEMM: C[M,N] (fp32) = A[M,K] @ Bt[N,K]^T, both bf16 row-major.
// 128x128 tile, BK=64 (128B LDS rows), 4 waves each owning a 64x64 quadrant.
// global_load_lds with pre-swizzled source; reads swizzled (byte^=(row&7)<<4)
// -> conflict-free ds_read_b128.  Grid is 1-D, XCD-swizzled (nwg%8==0).
// ---------------------------------------------------------------------------
__global__ __launch_bounds__(256) void gemm_bf16(const u16* __restrict__ A,
                                                 const u16* __restrict__ Bt,
                                                 float* __restrict__ C,
                                                 int M, int N, int K) {
  __shared__ u16 As[128 * 64];  // 16 KB, swizzled content
  __shared__ u16 Bs[128 * 64];  // 16 KB
  char* AsB = (char*)As;
  char* BsB = (char*)Bs;

  const int tid = threadIdx.x;
  const int l = tid & 63;
  const int l15 = l & 15;
  const int lg = l >> 4;
  const int w = tid >> 6;
  const int wr = (w >> 1) * 64;
  const int wc = (w & 1) * 64;

  const int nbx = N >> 7;
  int bid = (int)blockIdx.x;
  const int cpx = (int)gridDim.x >> 3;  // nwg % 8 == 0 (bijective XCD swizzle)
  bid = (bid & 7) * cpx + (bid >> 3);
  const int row0 = (bid / nbx) * 128;
  const int col0 = (bid % nbx) * 128;

  // staging: 4 chunks of 16B per thread per matrix; source pre-swizzled so
  // the linear LDS write lands data where the swizzled read expects it.
  size_t abase[4], bbase[4];
  int ldso[4];
#pragma unroll
  for (int i = 0; i < 4; ++i) {
    const int c = tid + i * 256;
    const int o = c * 16;           // linear LDS byte offset
    const int r = o >> 7;           // tile row
    const int sb = (o & 127) ^ ((r & 7) << 4);  // swizzled byte-in-row
    ldso[i] = o;
    abase[i] = (size_t)(row0 + r) * K + (sb >> 1);
    bbase[i] = (size_t)(col0 + r) * K + (sb >> 1);
  }
  const int xr = (l15 & 7) << 4;

  f32x4 acc[4][4];
#pragma unroll
  for (int m = 0; m < 4; ++m)
#pragma unroll
    for (int n = 0; n < 4; ++n) acc[m][n] = (f32x4)0.f;

  for (int k0 = 0; k0 < K; k0 += 64) {
    __syncthreads();
#pragma unroll
    for (int i = 0; i < 4; ++i) gload_lds16(A + abase[i] + k0, AsB + ldso[i]);
#pragma unroll
    for (int i = 0; i < 4; ++i) gload_lds16(Bt + bbase[i] + k0, BsB + ldso[i]);
    __syncthreads();  // compiler drains vmcnt before barrier

#pragma unroll
    for (int kk = 0; kk < 2; ++kk) {
      const int kb = kk * 64 + lg * 16;
      short8 a[4], b[4];
#pragma unroll
      for (int m = 0; m < 4; ++m)
        a[m] = *(const short8*)(AsB + (wr + m * 16 + l15) * 128 + (kb ^ xr));
#pragma unroll
      for (int n = 0; n < 4; ++n)
        b[n] = *(const short8*)(BsB + (wc + n * 16 + l15) * 128 + (kb ^ xr));
#pragma unroll
      for (int m = 0; m < 4; ++m)
#pragma unroll
        for (int n = 0; n < 4; ++n)
          acc[m][n] =
              __builtin_amdgcn_mfma_f32_16x16x32_bf16(a[m], b[n], acc[m][n], 0, 0, 0);
    }
  }

#pragma unroll
  for (int m = 0; m < 4; ++m)
#pragma unroll
    for (int n = 0; n < 4; ++n)
#pragma unroll
      for (int r = 0; r < 4; ++r)
        C[(size_t)(row0 + wr + m * 16 + lg * 4 + r) * N + col0 + wc + n * 16 +
          l15] = acc[m][n][r];
}

// ---------------------------------------------------------------------------
// fp32 -> bf16 flat convert (n % 2048 == 0 in all uses).
// ---------------------------------------------------------------------------
__global__ __launch_bounds__(256) void conv_bf16(const float* __restrict__ s,
                                                 u16* __restrict__ d, int n) {
  const int i = (blockIdx.x * 256 + threadIdx.x) * 8;
  if (i >= n) return;
  const float4 a = *(const float4*)(s + i);
  const float4 b = *(const float4*)(s + i + 4);
  u32x4 pk;
  pk[0] = pack2(a.x, a.y); pk[1] = pack2(a.z, a.w);
  pk[2] = pack2(b.x, b.y); pk[3] = pack2(b.z, b.w);
  *(u32x4*)(d + i) = pk;
}

// fp32 [R][Cn] -> bf16 [Cn][R] transpose (R,Cn % 32 == 0).
__global__ __launch_bounds__(256) void transpose_bf16(const float* __restrict__ s,
                                                      u16* __restrict__ d,
                                                      int R, int Cn) {
  __shared__ float t[32][33];
  const int tx = threadIdx.x & 31;
  const int ty = threadIdx.x >> 5;
  const int x = blockIdx.x * 32 + tx;
#pragma unroll
  for (int j = 0; j < 4; ++j)
    t[ty + j * 8][tx] = s[(size_t)(blockIdx.y * 32 + ty + j * 8) * Cn + x];
  __syncthreads();
  const int xo = blockIdx.y * 32 + tx;
#pragma unroll
  for (int j = 0; j < 4; ++j)
    d[(size_t)(blockIdx.x * 32 + ty + j * 8) * R + xo] = f2bf(t[tx][ty + j * 8]);
}

// kv [4096][256] fp32, cols 128..255 -> v_bf [4096][128] bf16.
__global__ __launch_bounds__(256) void conv_v(const float* __restrict__ kv,
                                              u16* __restrict__ v) {
  const int gid = blockIdx.x * 256 + threadIdx.x;
  const int row = gid >> 4;
  const int c8 = (gid & 15) * 8;
  const float* s = kv + (size_t)row * 256 + 128 + c8;
  const float4 a = *(const float4*)s;
  const float4 b = *(const float4*)(s + 4);
  u32x4 pk;
  pk[0] = pack2(a.x, a.y); pk[1] = pack2(a.z, a.w);
  pk[2] = pack2(b.x, b.y); pk[3] = pack2(b.z, b.w);
  *(u32x4*)(v + (size_t)row * 128 + c8) = pk;
}

// ---------------------------------------------------------------------------
// fp32 LayerNorm (D=128) + interleaved RoPE, bf16 out (scale folded for q).
// ---------------------------------------------------------------------------
__global__ __launch_bounds__(128) void ln_rope(const float* __restrict__ X,
                                               int xstride, u16* __restrict__ Y,
                                               const float* __restrict__ g,
                                               const float* __restrict__ be,
                                               const float* __restrict__ fc,
                                               const float* __restrict__ fs,
                                               int heads, float oscale) {
  __shared__ float red[4];
  const int row = blockIdx.x;
  const int d = threadIdx.x;
  const int s = (row / heads) % S_SZ;

  const float x = X[(size_t)row * xstride + d];
  float v1 = x, v2 = x * x;
#pragma unroll
  for (int off = 1; off < 64; off <<= 1) {
    v1 += __shfl_xor(v1, off);
    v2 += __shfl_xor(v2, off);
  }
  if ((d & 63) == 0) { red[(d >> 6) * 2] = v1; red[(d >> 6) * 2 + 1] = v2; }
  __syncthreads();
  const float mean = (red[0] + red[2]) * (1.f / 128.f);
  const float var = (red[1] + red[3]) * (1.f / 128.f) - mean * mean;
  const float inv = rsqrtf(var + EPS_LN);
  const float y = (x - mean) * inv * g[d] + be[d];
  const float yp = __shfl_xor(y, 1);
  const float c = fc[(size_t)s * D_SZ + d];
  const float sn = fs[(size_t)s * D_SZ + d];
  const float o = (d & 1) ? (yp * sn + y * c) : (y * c - yp * sn);
  Y[(size_t)row * D_SZ + d] = f2bf(o * oscale);
}

// ---------------------------------------------------------------------------
// Flash-style bf16 MFMA MQA attention (HKV=1), bf16 in / bf16 out.
// Same structure as the validated round-2 kernel, minus fp32 conversions.
// ---------------------------------------------------------------------------
__global__ __launch_bounds__(256) void attn_mfma(const u16* __restrict__ Qbf,
                                                 const u16* __restrict__ Kbf,
                                                 const u16* __restrict__ Vbf,
                                                 u16* __restrict__ Obf) {
  __shared__ u16 KsS[64 * 128];
  __shared__ u16 VtS[128 * 64];
  __shared__ u16 PsS[4][16 * 64];

  const int tid = threadIdx.x;
  const int l = tid & 63;
  const int w = tid >> 6;
  const int l15 = l & 15;
  const int lg = l >> 4;

  const int qt = blockIdx.x & 31;
  const int h = (blockIdx.x >> 5) % H_SZ;
  const int b = blockIdx.x / (32 * H_SZ);

  char* KsB = (char*)KsS;
  char* VtB = (char*)VtS;
  char* PsB = (char*)&PsS[w][0];

  short8 qa[4];
  {
    const int qrow = qt * 64 + w * 16 + l15;
    const u16* qp = Qbf + ((size_t)(b * S_SZ + qrow) * H_SZ + h) * D_SZ + lg * 8;
#pragma unroll
    for (int kt = 0; kt < 4; ++kt) qa[kt] = *(const short8*)(qp + kt * 32);
  }

  f32x4 oacc[8];
#pragma unroll
  for (int dt = 0; dt < 8; ++dt) oacc[dt] = (f32x4)0.f;
  float m_run[4] = {-1e30f, -1e30f, -1e30f, -1e30f};
  float l_run[4] = {0.f, 0.f, 0.f, 0.f};

  const int krow = tid >> 2;
  const int kq = tid & 3;
  const int vk0 = (tid & 31) * 2;
  const int vdb = (tid >> 5) * 16;

  for (int kv0 = 0; kv0 < S_SZ; kv0 += 64) {
    __syncthreads();
    // stage K (swizzled bf16 copy)
    {
      const u16* kp = Kbf + (size_t)(b * S_SZ + kv0 + krow) * D_SZ + kq * 32;
      const int xr = (krow & 7) << 4;
#pragma unroll
      for (int i = 0; i < 4; ++i)
        *(short8*)(KsB + krow * 256 + ((kq * 64 + i * 16) ^ xr)) =
            *(const short8*)(kp + i * 8);
    }
    // stage V transposed (swizzled)
    {
      const u16* vp0 = Vbf + (size_t)(b * S_SZ + kv0 + vk0) * D_SZ + vdb;
      const u16* vp1 = vp0 + D_SZ;
      const short8 r0a = *(const short8*)vp0;
      const short8 r0b = *(const short8*)(vp0 + 8);
      const short8 r1a = *(const short8*)vp1;
      const short8 r1b = *(const short8*)(vp1 + 8);
#pragma unroll
      for (int i = 0; i < 8; ++i) {
        const int d0 = vdb + i;
        *(unsigned*)(VtB + d0 * 128 + ((vk0 * 2) ^ ((d0 & 7) << 4))) =
            (unsigned)(u16)r0a[i] | ((unsigned)(u16)r1a[i] << 16);
        const int d1 = vdb + 8 + i;
        *(unsigned*)(VtB + d1 * 128 + ((vk0 * 2) ^ ((d1 & 7) << 4))) =
            (unsigned)(u16)r0b[i] | ((unsigned)(u16)r1b[i] << 16);
      }
    }
    __syncthreads();

    // QK^T
    f32x4 sacc[4];
#pragma unroll
    for (int c = 0; c < 4; ++c) sacc[c] = (f32x4)0.f;
#pragma unroll
    for (int c = 0; c < 4; ++c) {
      const int kr = c * 16 + l15;
      const int xr = (kr & 7) << 4;
#pragma unroll
      for (int kt = 0; kt < 4; ++kt) {
        const short8 kb =
            *(const short8*)(KsB + kr * 256 + ((kt * 64 + lg * 16) ^ xr));
        sacc[c] =
            __builtin_amdgcn_mfma_f32_16x16x32_bf16(qa[kt], kb, sacc[c], 0, 0, 0);
      }
    }

    // online softmax
    float mx[4], mnew[4], corr[4], psum[4];
#pragma unroll
    for (int r = 0; r < 4; ++r)
      mx[r] = fmaxf(fmaxf(sacc[0][r], sacc[1][r]),
                    fmaxf(sacc[2][r], sacc[3][r]));
#pragma unroll
    for (int off = 1; off < 16; off <<= 1)
#pragma unroll
      for (int r = 0; r < 4; ++r) mx[r] = fmaxf(mx[r], __shfl_xor(mx[r], off));
#pragma unroll
    for (int r = 0; r < 4; ++r) {
      mnew[r] = fmaxf(m_run[r], mx[r]);
      corr[r] = __expf(m_run[r] - mnew[r]);
      m_run[r] = mnew[r];
      psum[r] = 0.f;
    }
#pragma unroll
    for (int c = 0; c < 4; ++c)
#pragma unroll
      for (int r = 0; r < 4; ++r) {
        const float p = __expf(sacc[c][r] - mnew[r]);
        psum[r] += p;
        const int row = lg * 4 + r;
        *(u16*)(PsB + row * 128 +
                (((c * 16 + l15) * 2) ^ ((row & 7) << 4))) = f2bf(p);
      }
#pragma unroll
    for (int off = 1; off < 16; off <<= 1)
#pragma unroll
      for (int r = 0; r < 4; ++r) psum[r] += __shfl_xor(psum[r], off);
#pragma unroll
    for (int r = 0; r < 4; ++r) l_run[r] = l_run[r] * corr[r] + psum[r];
#pragma unroll
    for (int dt = 0; dt < 8; ++dt)
#pragma unroll
      for (int r = 0; r < 4; ++r) oacc[dt][r] *= corr[r];

    // PV
#pragma unroll
    for (int kt2 = 0; kt2 < 2; ++kt2) {
      const short8 pa = *(const short8*)(
          PsB + l15 * 128 + ((kt2 * 64 + lg * 16) ^ ((l15 & 7) << 4)));
#pragma unroll
      for (int dt = 0; dt < 8; ++dt) {
        const int vr = dt * 16 + l15;
        const short8 vb = *(const short8*)(
            VtB + vr * 128 + ((kt2 * 64 + lg * 16) ^ ((vr & 7) << 4)));
        oacc[dt] =
            __builtin_amdgcn_mfma_f32_16x16x32_bf16(pa, vb, oacc[dt], 0, 0, 0);
      }
    }
  }

  float inv[4];
#pragma unroll
  for (int r = 0; r < 4; ++r) inv[r] = 1.f / l_run[r];
  const size_t obase =
      ((size_t)(b * S_SZ + qt * 64 + w * 16)) * (H_SZ * D_SZ) + h * D_SZ;
#pragma unroll
  for (int dt = 0; dt < 8; ++dt)
#pragma unroll
    for (int r = 0; r < 4; ++r)
      Obf[obase + (size_t)(lg * 4 + r) * (H_SZ * D_SZ) + dt * 16 + l15] =
          f2bf(oacc[dt][r] * inv[r]);
}

// ---------------------------------------------------------------------------
extern "C" void kernel_launch(void* const* d_in, const int* in_sizes, int n_in,
                              void* d_out, int out_size, void* d_ws,
                              size_t ws_size, hipStream_t stream) {
  const float* hidden = (const float*)d_in[0];
  const float* fcos = (const float*)d_in[1];
  const float* fsin = (const float*)d_in[2];
  const float* w_q = (const float*)d_in[3];
  const float* w_k = (const float*)d_in[4];
  const float* w_v = (const float*)d_in[5];
  const float* w_o = (const float*)d_in[6];
  const float* ln_q_w = (const float*)d_in[7];
  const float* ln_q_b = (const float*)d_in[8];
  const float* ln_k_w = (const float*)d_in[9];
  const float* ln_k_b = (const float*)d_in[10];
  float* out = (float*)d_out;

  const int M = B_SZ * S_SZ;  // 4096

  // workspace layout (bytes)
  char* ws = (char*)d_ws;
  u16* hid_bf = (u16*)ws;                          // 25165824 B  [aliased a_bf]
  u16* wqt = (u16*)(ws + 25165824);                // 18874368 B  [reused: w_o^T]
  u16* wkvt = (u16*)(ws + 44040192);               //  1572864 B
  float* kv_buf = (float*)(ws + 45613056);         //  4194304 B
  u16* k_bf = (u16*)(ws + 49807360);               //  1048576 B
  u16* v_bf = (u16*)(ws + 50855936);               //  1048576 B
  u16* q_bf = (u16*)(ws + 51904512);               // 25165824 B
  u16* a_bf = hid_bf;  // attn out, reuses hid_bf (dead after kv GEMM)
  float* q_f32 = out;  // fp32 q projection lives in d_out until ln_rope

  // 1. hidden -> bf16
  conv_bf16<<<(M * DIM_SZ) / 2048, 256, 0, stream>>>(hidden, hid_bf, M * DIM_SZ);
  // 2-4. weight transposes -> bf16 [N][K]
  transpose_bf16<<<dim3(DIM_SZ / 32, DIM_SZ / 32), 256, 0, stream>>>(
      w_q, wqt, DIM_SZ, DIM_SZ);
  transpose_bf16<<<dim3(D_SZ / 32, DIM_SZ / 32), 256, 0, stream>>>(
      w_k, wkvt, DIM_SZ, D_SZ);
  transpose_bf16<<<dim3(D_SZ / 32, DIM_SZ / 32), 256, 0, stream>>>(
      w_v, wkvt + (size_t)D_SZ * DIM_SZ, DIM_SZ, D_SZ);

  // 5. q = hidden @ w_q  (fp32 out for LN)
  gemm_bf16<<<(M / 128) * (DIM_SZ / 128), 256, 0, stream>>>(
      hid_bf, wqt, q_f32, M, DIM_SZ, DIM_SZ);
  // 6. kv = hidden @ [w_k|w_v]
  gemm_bf16<<<(M / 128) * (256 / 128), 256, 0, stream>>>(hid_bf, wkvt, kv_buf,
                                                         M, 256, DIM_SZ);
  // 7. w_o^T into wqt (q GEMM done; stream-ordered)
  transpose_bf16<<<dim3(DIM_SZ / 32, DIM_SZ / 32), 256, 0, stream>>>(
      w_o, wqt, DIM_SZ, DIM_SZ);

  // 8-10. LN+RoPE -> bf16 (q pre-scaled by 1/sqrt(D)); v extract -> bf16
  ln_rope<<<M * H_SZ, 128, 0, stream>>>(q_f32, 128, q_bf, ln_q_w, ln_q_b, fcos,
                                        fsin, H_SZ, 0.08838834764831845f);
  ln_rope<<<M, 128, 0, stream>>>(kv_buf, 256, k_bf, ln_k_w, ln_k_b, fcos, fsin,
                                 1, 1.0f);
  conv_v<<<(M * 128) / 2048, 256, 0, stream>>>(kv_buf, v_bf);

  // 11. attention -> bf16
  attn_mfma<<<B_SZ * H_SZ * 32, 256, 0, stream>>>(q_bf, k_bf, v_bf, a_bf);

  // 12. out = attn @ w_o  (fp32 out)
  gemm_bf16<<<(M / 128) * (DIM_SZ / 128), 256, 0, stream>>>(a_bf, wqt, out, M,
                                                            DIM_SZ, DIM_SZ);
}

// Round 4
// 561.831 us; speedup vs baseline: 10.3569x; 1.1468x over previous
//
#include <hip/hip_runtime.h>
#include <hip/hip_bf16.h>

#define B_SZ 2
#define S_SZ 2048
#define DIM_SZ 3072
#define H_SZ 24
#define D_SZ 128
#define EPS_LN 1e-6f

typedef __attribute__((ext_vector_type(8))) short short8;
typedef __attribute__((ext_vector_type(4))) float f32x4;
typedef __attribute__((ext_vector_type(16))) float f32x16;
typedef __attribute__((ext_vector_type(4))) unsigned int u32x4;
typedef unsigned short u16;

__device__ __forceinline__ u16 f2bf(float f) {
  union { float f; unsigned u; } x; x.f = f;
  unsigned r = x.u + 0x7fffu + ((x.u >> 16) & 1u);  // RNE
  return (u16)(r >> 16);
}
__device__ __forceinline__ unsigned pack2(float a, float b) {
  return (unsigned)f2bf(a) | ((unsigned)f2bf(b) << 16);
}

// async global->LDS, 16B per lane (wave-uniform LDS base + lane*16).
typedef const __attribute__((address_space(1))) void* gas_ptr;
typedef __attribute__((address_space(3))) void* las_ptr;
__device__ __forceinline__ void gload_lds16(const void* g, void* l) {
  __builtin_amdgcn_global_load_lds(
      reinterpret_cast<gas_ptr>(reinterpret_cast<uintptr_t>(g)),
      reinterpret_cast<las_ptr>(reinterpret_cast<uintptr_t>(l)), 16, 0, 0);
}

// ---------------------------------------------------------------------------
// bf16 MFMA GEMM: C[M,N] (fp32) = A[M,K] @ Bt[N,K]^T   (unchanged, validated)
// ---------------------------------------------------------------------------
__global__ __launch_bounds__(256) void gemm_bf16(const u16* __restrict__ A,
                                                 const u16* __restrict__ Bt,
                                                 float* __restrict__ C,
                                                 int M, int N, int K) {
  __shared__ u16 As[128 * 64];
  __shared__ u16 Bs[128 * 64];
  char* AsB = (char*)As;
  char* BsB = (char*)Bs;

  const int tid = threadIdx.x;
  const int l = tid & 63;
  const int l15 = l & 15;
  const int lg = l >> 4;
  const int w = tid >> 6;
  const int wr = (w >> 1) * 64;
  const int wc = (w & 1) * 64;

  const int nbx = N >> 7;
  int bid = (int)blockIdx.x;
  const int cpx = (int)gridDim.x >> 3;
  bid = (bid & 7) * cpx + (bid >> 3);
  const int row0 = (bid / nbx) * 128;
  const int col0 = (bid % nbx) * 128;

  size_t abase[4], bbase[4];
  int ldso[4];
#pragma unroll
  for (int i = 0; i < 4; ++i) {
    const int c = tid + i * 256;
    const int o = c * 16;
    const int r = o >> 7;
    const int sb = (o & 127) ^ ((r & 7) << 4);
    ldso[i] = o;
    abase[i] = (size_t)(row0 + r) * K + (sb >> 1);
    bbase[i] = (size_t)(col0 + r) * K + (sb >> 1);
  }
  const int xr = (l15 & 7) << 4;

  f32x4 acc[4][4];
#pragma unroll
  for (int m = 0; m < 4; ++m)
#pragma unroll
    for (int n = 0; n < 4; ++n) acc[m][n] = (f32x4)0.f;

  for (int k0 = 0; k0 < K; k0 += 64) {
    __syncthreads();
#pragma unroll
    for (int i = 0; i < 4; ++i) gload_lds16(A + abase[i] + k0, AsB + ldso[i]);
#pragma unroll
    for (int i = 0; i < 4; ++i) gload_lds16(Bt + bbase[i] + k0, BsB + ldso[i]);
    __syncthreads();

#pragma unroll
    for (int kk = 0; kk < 2; ++kk) {
      const int kb = kk * 64 + lg * 16;
      short8 a[4], b[4];
#pragma unroll
      for (int m = 0; m < 4; ++m)
        a[m] = *(const short8*)(AsB + (wr + m * 16 + l15) * 128 + (kb ^ xr));
#pragma unroll
      for (int n = 0; n < 4; ++n)
        b[n] = *(const short8*)(BsB + (wc + n * 16 + l15) * 128 + (kb ^ xr));
#pragma unroll
      for (int m = 0; m < 4; ++m)
#pragma unroll
        for (int n = 0; n < 4; ++n)
          acc[m][n] =
              __builtin_amdgcn_mfma_f32_16x16x32_bf16(a[m], b[n], acc[m][n], 0, 0, 0);
    }
  }

#pragma unroll
  for (int m = 0; m < 4; ++m)
#pragma unroll
    for (int n = 0; n < 4; ++n)
#pragma unroll
      for (int r = 0; r < 4; ++r)
        C[(size_t)(row0 + wr + m * 16 + lg * 4 + r) * N + col0 + wc + n * 16 +
          l15] = acc[m][n][r];
}

// ---------------------------------------------------------------------------
// fp32 -> bf16 flat convert
// ---------------------------------------------------------------------------
__global__ __launch_bounds__(256) void conv_bf16(const float* __restrict__ s,
                                                 u16* __restrict__ d, int n) {
  const int i = (blockIdx.x * 256 + threadIdx.x) * 8;
  if (i >= n) return;
  const float4 a = *(const float4*)(s + i);
  const float4 b = *(const float4*)(s + i + 4);
  u32x4 pk;
  pk[0] = pack2(a.x, a.y); pk[1] = pack2(a.z, a.w);
  pk[2] = pack2(b.x, b.y); pk[3] = pack2(b.z, b.w);
  *(u32x4*)(d + i) = pk;
}

// fp32 [R][Cn] -> bf16 [Cn][R] transpose
__global__ __launch_bounds__(256) void transpose_bf16(const float* __restrict__ s,
                                                      u16* __restrict__ d,
                                                      int R, int Cn) {
  __shared__ float t[32][33];
  const int tx = threadIdx.x & 31;
  const int ty = threadIdx.x >> 5;
  const int x = blockIdx.x * 32 + tx;
#pragma unroll
  for (int j = 0; j < 4; ++j)
    t[ty + j * 8][tx] = s[(size_t)(blockIdx.y * 32 + ty + j * 8) * Cn + x];
  __syncthreads();
  const int xo = blockIdx.y * 32 + tx;
#pragma unroll
  for (int j = 0; j < 4; ++j)
    d[(size_t)(blockIdx.x * 32 + ty + j * 8) * R + xo] = f2bf(t[tx][ty + j * 8]);
}

// kv [B*S][256] fp32 cols 128..255  ->  vt [B][128][S] bf16 (V transposed)
__global__ __launch_bounds__(256) void transpose_v(const float* __restrict__ kv,
                                                   u16* __restrict__ vt) {
  __shared__ float t[32][33];
  const int tx = threadIdx.x & 31;
  const int ty = threadIdx.x >> 5;
  const int st = blockIdx.x;   // s tile (64)
  const int dt = blockIdx.y;   // d tile (4)
  const int b = blockIdx.z;
#pragma unroll
  for (int j = 0; j < 4; ++j)
    t[ty + j * 8][tx] =
        kv[(size_t)(b * S_SZ + st * 32 + ty + j * 8) * 256 + 128 + dt * 32 + tx];
  __syncthreads();
#pragma unroll
  for (int j = 0; j < 4; ++j)
    vt[(size_t)(b * D_SZ + dt * 32 + ty + j * 8) * S_SZ + st * 32 + tx] =
        f2bf(t[tx][ty + j * 8]);
}

// ---------------------------------------------------------------------------
// fp32 LayerNorm (D=128) + interleaved RoPE, bf16 out (scale folded for q).
// ---------------------------------------------------------------------------
__global__ __launch_bounds__(128) void ln_rope(const float* __restrict__ X,
                                               int xstride, u16* __restrict__ Y,
                                               const float* __restrict__ g,
                                               const float* __restrict__ be,
                                               const float* __restrict__ fc,
                                               const float* __restrict__ fs,
                                               int heads, float oscale) {
  __shared__ float red[4];
  const int row = blockIdx.x;
  const int d = threadIdx.x;
  const int s = (row / heads) % S_SZ;

  const float x = X[(size_t)row * xstride + d];
  float v1 = x, v2 = x * x;
#pragma unroll
  for (int off = 1; off < 64; off <<= 1) {
    v1 += __shfl_xor(v1, off);
    v2 += __shfl_xor(v2, off);
  }
  if ((d & 63) == 0) { red[(d >> 6) * 2] = v1; red[(d >> 6) * 2 + 1] = v2; }
  __syncthreads();
  const float mean = (red[0] + red[2]) * (1.f / 128.f);
  const float var = (red[1] + red[3]) * (1.f / 128.f) - mean * mean;
  const float inv = rsqrtf(var + EPS_LN);
  const float y = (x - mean) * inv * g[d] + be[d];
  const float yp = __shfl_xor(y, 1);
  const float c = fc[(size_t)s * D_SZ + d];
  const float sn = fs[(size_t)s * D_SZ + d];
  const float o = (d & 1) ? (yp * sn + y * c) : (y * c - yp * sn);
  Y[(size_t)row * D_SZ + d] = f2bf(o * oscale);
}

// ---------------------------------------------------------------------------
// Flash MQA attention, 32x32x16 MFMA, swapped QK^T (S^T = K·Q^T) so softmax is
// fully in-register (lane l owns q-row l&31; lanes l and l^32 hold
// complementary key quads).  K and V^T staged via global_load_lds (pre-swizzled
// sources, linear LDS dest), double-buffered, one barrier per 64-key tile.
// Block = 4 waves; wave w owns q-rows [qt*128 + w*32, +32).
//   C/D layout (verified m74/m101): col=lane&31, row=(r&3)+8*(r>>2)+4*(lane>>5)
//   A/B frag: row(col)=lane&31, k=(lane>>5)*8+i
// ---------------------------------------------------------------------------
__global__ __launch_bounds__(256) void attn_mfma32(const u16* __restrict__ Qbf,
                                                   const u16* __restrict__ Kbf,
                                                   const u16* __restrict__ Vt,
                                                   u16* __restrict__ Obf) {
  // per buffer: K tile 64x128 u16 (16 KB, 256B rows) then V^T tile packed as
  // 64 rows x 256B (row r = d=r | d=r+64) (16 KB).
  __shared__ char LB[2][32768];

  const int tid = threadIdx.x;
  const int l = tid & 63;
  const int w = tid >> 6;
  const int l31 = l & 31;
  const int hh = l >> 5;

  const int bid = blockIdx.x;
  const int qt = bid & 15;
  const int h = (bid >> 4) % H_SZ;
  const int b = bid / (16 * H_SZ);

  // ---- Q fragments (B operand): lane holds q-row l31, k = hh*8+i per dk ----
  short8 qf[8];
  {
    const u16* qp =
        Qbf + ((size_t)(b * S_SZ + qt * 128 + w * 32 + l31) * H_SZ + h) * D_SZ +
        hh * 8;
#pragma unroll
    for (int dk = 0; dk < 8; ++dk) qf[dk] = *(const short8*)(qp + dk * 16);
  }

  // ---- staging descriptors (4 K-chunks + 4 V-chunks of 16B per thread) ----
  const char* kSrc[4];
  const char* vSrc[4];
  int kLds[4], vLds[4];
#pragma unroll
  for (int i = 0; i < 4; ++i) {
    const int o = (tid + i * 256) * 16;
    {  // K: row = key (256B rows), swz bits 4-6 + bit7
      const int r = o >> 8;
      const int sc = (o & 255) ^ ((r & 7) << 4) ^ (((r >> 3) & 1) << 7);
      kSrc[i] = (const char*)Kbf + (size_t)(b * S_SZ + r) * 256 + sc;
      kLds[i] = o;
    }
    {  // V^T packed: LDS row r holds d=r (bytes 0-127) and d=r+64 (128-255)
      const int r = o >> 8;
      const int half = (o >> 7) & 1;
      const int d = half * 64 + r;
      const int sc = (o & 127) ^ ((r & 7) << 4);
      vSrc[i] = (const char*)Vt + (size_t)(b * D_SZ + d) * (S_SZ * 2) + sc;
      vLds[i] = o;
    }
  }

  f32x16 oa[4];
#pragma unroll
  for (int db = 0; db < 4; ++db) oa[db] = (f32x16)0.f;
  float m_run = -1e30f, l_run = 0.f;

  const int swzK = ((l31 & 7) << 4) ^ (((l31 >> 3) & 1) << 7);

  // prologue: stage tile 0
#pragma unroll
  for (int i = 0; i < 4; ++i) {
    gload_lds16(kSrc[i], &LB[0][kLds[i]]);
    gload_lds16(vSrc[i], &LB[0][16384 + vLds[i]]);
  }

  for (int t = 0; t < S_SZ / 64; ++t) {
    __syncthreads();  // drains vmcnt -> tile t ready; all waves past tile t-1
    if (t < S_SZ / 64 - 1) {
      const int nb = (t + 1) & 1;
#pragma unroll
      for (int i = 0; i < 4; ++i) {
        gload_lds16(kSrc[i] + (size_t)(t + 1) * 16384, &LB[nb][kLds[i]]);
        gload_lds16(vSrc[i] + (t + 1) * 128, &LB[nb][16384 + vLds[i]]);
      }
    }
    const char* Kb = &LB[t & 1][0];
    const char* Vb = &LB[t & 1][16384];

    // ---- QK^T: S^T[key][q], keys kb*32+crow(r,hh) held per lane ----
    f32x16 s0 = (f32x16)0.f, s1 = (f32x16)0.f;
    __builtin_amdgcn_s_setprio(1);
#pragma unroll
    for (int dk = 0; dk < 8; ++dk) {
      const int colb = (dk * 32 + hh * 16) ^ swzK;
      const short8 a0 = *(const short8*)(Kb + l31 * 256 + colb);
      const short8 a1 = *(const short8*)(Kb + (32 + l31) * 256 + colb);
      s0 = __builtin_amdgcn_mfma_f32_32x32x16_bf16(a0, qf[dk], s0, 0, 0, 0);
      s1 = __builtin_amdgcn_mfma_f32_32x32x16_bf16(a1, qf[dk], s1, 0, 0, 0);
    }
    __builtin_amdgcn_s_setprio(0);

    // ---- online softmax, in-register (defer-max, THR=8) ----
    float pm = s0[0];
#pragma unroll
    for (int r = 1; r < 16; ++r) pm = fmaxf(pm, s0[r]);
#pragma unroll
    for (int r = 0; r < 16; ++r) pm = fmaxf(pm, s1[r]);
    pm = fmaxf(pm, __shfl_xor(pm, 32));
    if (!__all(pm <= m_run + 8.f)) {
      const float mnew = fmaxf(m_run, pm);
      const float corr = __expf(m_run - mnew);
      m_run = mnew;
      l_run *= corr;
#pragma unroll
      for (int r = 0; r < 16; ++r) {
        const float cq = __shfl(corr, (r & 3) + 8 * (r >> 2) + 4 * hh);
#pragma unroll
        for (int db = 0; db < 4; ++db) oa[db][r] *= cq;
      }
    }
    float ps = 0.f;
#pragma unroll
    for (int r = 0; r < 16; ++r) { s0[r] = __expf(s0[r] - m_run); ps += s0[r]; }
#pragma unroll
    for (int r = 0; r < 16; ++r) { s1[r] = __expf(s1[r] - m_run); ps += s1[r]; }
    ps += __shfl_xor(ps, 32);
    l_run += ps;

    // ---- PV: O[q][d] += P[q][key] V[key][d] ----
#pragma unroll
    for (int ks = 0; ks < 4; ++ks) {
      const f32x16& sv = (ks < 2) ? s0 : s1;
      const int rb = (ks & 1) * 8;
      const unsigned x0 = pack2(sv[rb + 0], sv[rb + 1]);
      const unsigned y0 = pack2(sv[rb + 4], sv[rb + 5]);
      const unsigned x1 = pack2(sv[rb + 2], sv[rb + 3]);
      const unsigned y1 = pack2(sv[rb + 6], sv[rb + 7]);
      const unsigned sy0 = (unsigned)__shfl_xor((int)y0, 32);
      const unsigned sy1 = (unsigned)__shfl_xor((int)y1, 32);
      const unsigned sx0 = (unsigned)__shfl_xor((int)x0, 32);
      const unsigned sx1 = (unsigned)__shfl_xor((int)x1, 32);
      u32x4 paw;
      paw[0] = hh ? sy0 : x0;
      paw[1] = hh ? sy1 : x1;
      paw[2] = hh ? y0 : sx0;
      paw[3] = hh ? y1 : sx1;
      const short8 pa = *(const short8*)&paw;
      __builtin_amdgcn_s_setprio(1);
#pragma unroll
      for (int db = 0; db < 4; ++db) {
        const int d = db * 32 + l31;
        const int lr = d & 63;
        const int cb = (((d >> 6) << 7) | ((ks * 32 + hh * 16) ^ ((lr & 7) << 4)));
        const short8 vb = *(const short8*)(Vb + lr * 256 + cb);
        oa[db] = __builtin_amdgcn_mfma_f32_32x32x16_bf16(pa, vb, oa[db], 0, 0, 0);
      }
      __builtin_amdgcn_s_setprio(0);
    }
  }

  // ---- epilogue: normalize, store bf16 [B,S,H*D] ----
  const float linv = 1.f / l_run;
#pragma unroll
  for (int r = 0; r < 16; ++r) {
    const int crow = (r & 3) + 8 * (r >> 2) + 4 * hh;
    const float inv = __shfl(linv, crow);
    u16* op = Obf + (size_t)(b * S_SZ + qt * 128 + w * 32 + crow) * (H_SZ * D_SZ) +
              h * D_SZ + l31;
#pragma unroll
    for (int db = 0; db < 4; ++db) op[db * 32] = f2bf(oa[db][r] * inv);
  }
}

// ---------------------------------------------------------------------------
extern "C" void kernel_launch(void* const* d_in, const int* in_sizes, int n_in,
                              void* d_out, int out_size, void* d_ws,
                              size_t ws_size, hipStream_t stream) {
  const float* hidden = (const float*)d_in[0];
  const float* fcos = (const float*)d_in[1];
  const float* fsin = (const float*)d_in[2];
  const float* w_q = (const float*)d_in[3];
  const float* w_k = (const float*)d_in[4];
  const float* w_v = (const float*)d_in[5];
  const float* w_o = (const float*)d_in[6];
  const float* ln_q_w = (const float*)d_in[7];
  const float* ln_q_b = (const float*)d_in[8];
  const float* ln_k_w = (const float*)d_in[9];
  const float* ln_k_b = (const float*)d_in[10];
  float* out = (float*)d_out;

  const int M = B_SZ * S_SZ;  // 4096

  char* ws = (char*)d_ws;
  u16* hid_bf = (u16*)ws;                       // 25165824 B [aliased a_bf]
  u16* wqt = (u16*)(ws + 25165824);             // 18874368 B [reused: w_o^T]
  u16* wkvt = (u16*)(ws + 44040192);            //  1572864 B
  float* kv_buf = (float*)(ws + 45613056);      //  4194304 B
  u16* k_bf = (u16*)(ws + 49807360);            //  1048576 B
  u16* vt_bf = (u16*)(ws + 50855936);           //  1048576 B (V^T [B][128][S])
  u16* q_bf = (u16*)(ws + 51904512);            // 25165824 B
  u16* a_bf = hid_bf;   // attn out reuses hid_bf (dead after kv GEMM)
  float* q_f32 = out;   // fp32 q projection lives in d_out until ln_rope

  conv_bf16<<<(M * DIM_SZ) / 2048, 256, 0, stream>>>(hidden, hid_bf, M * DIM_SZ);
  transpose_bf16<<<dim3(DIM_SZ / 32, DIM_SZ / 32), 256, 0, stream>>>(
      w_q, wqt, DIM_SZ, DIM_SZ);
  transpose_bf16<<<dim3(D_SZ / 32, DIM_SZ / 32), 256, 0, stream>>>(
      w_k, wkvt, DIM_SZ, D_SZ);
  transpose_bf16<<<dim3(D_SZ / 32, DIM_SZ / 32), 256, 0, stream>>>(
      w_v, wkvt + (size_t)D_SZ * DIM_SZ, DIM_SZ, D_SZ);

  gemm_bf16<<<(M / 128) * (DIM_SZ / 128), 256, 0, stream>>>(
      hid_bf, wqt, q_f32, M, DIM_SZ, DIM_SZ);
  gemm_bf16<<<(M / 128) * (256 / 128), 256, 0, stream>>>(hid_bf, wkvt, kv_buf,
                                                         M, 256, DIM_SZ);
  transpose_bf16<<<dim3(DIM_SZ / 32, DIM_SZ / 32), 256, 0, stream>>>(
      w_o, wqt, DIM_SZ, DIM_SZ);

  ln_rope<<<M * H_SZ, 128, 0, stream>>>(q_f32, 128, q_bf, ln_q_w, ln_q_b, fcos,
                                        fsin, H_SZ, 0.08838834764831845f);
  ln_rope<<<M, 128, 0, stream>>>(kv_buf, 256, k_bf, ln_k_w, ln_k_b, fcos, fsin,
                                 1, 1.0f);
  transpose_v<<<dim3(S_SZ / 32, D_SZ / 32, B_SZ), 256, 0, stream>>>(kv_buf,
                                                                    vt_bf);

  attn_mfma32<<<B_SZ * H_SZ * 16, 256, 0, stream>>>(q_bf, k_bf, vt_bf, a_bf);

  gemm_bf16<<<(M / 128) * (DIM_SZ / 128), 256, 0, stream>>>(a_bf, wqt, out, M,
                                                            DIM_SZ, DIM_SZ);
}

// Round 7
// 497.899 us; speedup vs baseline: 11.6867x; 1.1284x over previous
//
#include <hip/hip_runtime.h>
#include <hip/hip_bf16.h>

#define B_SZ 2
#define S_SZ 2048
#define DIM_SZ 3072
#define H_SZ 24
#define D_SZ 128
#define EPS_LN 1e-6f

typedef __attribute__((ext_vector_type(8))) short short8;
typedef __attribute__((ext_vector_type(4))) float f32x4;
typedef __attribute__((ext_vector_type(16))) float f32x16;
typedef __attribute__((ext_vector_type(4))) unsigned int u32x4;
typedef unsigned short u16;

__device__ __forceinline__ float fexp2(float x) {
  return __builtin_amdgcn_exp2f(x);  // v_exp_f32 (native base-2)
}

__device__ __forceinline__ u16 f2bf(float f) {
  union { float f; unsigned u; } x; x.f = f;
  unsigned r = x.u + 0x7fffu + ((x.u >> 16) & 1u);  // RNE
  return (u16)(r >> 16);
}
__device__ __forceinline__ unsigned pack2(float a, float b) {
  return (unsigned)f2bf(a) | ((unsigned)f2bf(b) << 16);
}

// async global->LDS, 16B per lane (wave-uniform LDS base + lane*16).
typedef const __attribute__((address_space(1))) void* gas_ptr;
typedef __attribute__((address_space(3))) void* las_ptr;
__device__ __forceinline__ void gload_lds16(const void* g, void* l) {
  __builtin_amdgcn_global_load_lds(
      reinterpret_cast<gas_ptr>(reinterpret_cast<uintptr_t>(g)),
      reinterpret_cast<las_ptr>(reinterpret_cast<uintptr_t>(l)), 16, 0, 0);
}

// ---------------------------------------------------------------------------
// bf16 MFMA GEMM: C[M,N] (fp32) = A[M,K] @ Bt[N,K]^T   (unchanged, validated)
// ---------------------------------------------------------------------------
__global__ __launch_bounds__(256) void gemm_bf16(const u16* __restrict__ A,
                                                 const u16* __restrict__ Bt,
                                                 float* __restrict__ C,
                                                 int M, int N, int K) {
  __shared__ u16 As[128 * 64];
  __shared__ u16 Bs[128 * 64];
  char* AsB = (char*)As;
  char* BsB = (char*)Bs;

  const int tid = threadIdx.x;
  const int l = tid & 63;
  const int l15 = l & 15;
  const int lg = l >> 4;
  const int w = tid >> 6;
  const int wr = (w >> 1) * 64;
  const int wc = (w & 1) * 64;

  const int nbx = N >> 7;
  int bid = (int)blockIdx.x;
  const int cpx = (int)gridDim.x >> 3;
  bid = (bid & 7) * cpx + (bid >> 3);
  const int row0 = (bid / nbx) * 128;
  const int col0 = (bid % nbx) * 128;

  size_t abase[4], bbase[4];
  int ldso[4];
#pragma unroll
  for (int i = 0; i < 4; ++i) {
    const int c = tid + i * 256;
    const int o = c * 16;
    const int r = o >> 7;
    const int sb = (o & 127) ^ ((r & 7) << 4);
    ldso[i] = o;
    abase[i] = (size_t)(row0 + r) * K + (sb >> 1);
    bbase[i] = (size_t)(col0 + r) * K + (sb >> 1);
  }
  const int xr = (l15 & 7) << 4;

  f32x4 acc[4][4];
#pragma unroll
  for (int m = 0; m < 4; ++m)
#pragma unroll
    for (int n = 0; n < 4; ++n) acc[m][n] = (f32x4)0.f;

  for (int k0 = 0; k0 < K; k0 += 64) {
    __syncthreads();
#pragma unroll
    for (int i = 0; i < 4; ++i) gload_lds16(A + abase[i] + k0, AsB + ldso[i]);
#pragma unroll
    for (int i = 0; i < 4; ++i) gload_lds16(Bt + bbase[i] + k0, BsB + ldso[i]);
    __syncthreads();

#pragma unroll
    for (int kk = 0; kk < 2; ++kk) {
      const int kb = kk * 64 + lg * 16;
      short8 a[4], b[4];
#pragma unroll
      for (int m = 0; m < 4; ++m)
        a[m] = *(const short8*)(AsB + (wr + m * 16 + l15) * 128 + (kb ^ xr));
#pragma unroll
      for (int n = 0; n < 4; ++n)
        b[n] = *(const short8*)(BsB + (wc + n * 16 + l15) * 128 + (kb ^ xr));
#pragma unroll
      for (int m = 0; m < 4; ++m)
#pragma unroll
        for (int n = 0; n < 4; ++n)
          acc[m][n] =
              __builtin_amdgcn_mfma_f32_16x16x32_bf16(a[m], b[n], acc[m][n], 0, 0, 0);
    }
  }

#pragma unroll
  for (int m = 0; m < 4; ++m)
#pragma unroll
    for (int n = 0; n < 4; ++n)
#pragma unroll
      for (int r = 0; r < 4; ++r)
        C[(size_t)(row0 + wr + m * 16 + lg * 4 + r) * N + col0 + wc + n * 16 +
          l15] = acc[m][n][r];
}

// ---------------------------------------------------------------------------
// fp32 -> bf16 flat convert
// ---------------------------------------------------------------------------
__global__ __launch_bounds__(256) void conv_bf16(const float* __restrict__ s,
                                                 u16* __restrict__ d, int n) {
  const int i = (blockIdx.x * 256 + threadIdx.x) * 8;
  if (i >= n) return;
  const float4 a = *(const float4*)(s + i);
  const float4 b = *(const float4*)(s + i + 4);
  u32x4 pk;
  pk[0] = pack2(a.x, a.y); pk[1] = pack2(a.z, a.w);
  pk[2] = pack2(b.x, b.y); pk[3] = pack2(b.z, b.w);
  *(u32x4*)(d + i) = pk;
}

// fp32 [R][Cn] -> bf16 [Cn][R] transpose
__global__ __launch_bounds__(256) void transpose_bf16(const float* __restrict__ s,
                                                      u16* __restrict__ d,
                                                      int R, int Cn) {
  __shared__ float t[32][33];
  const int tx = threadIdx.x & 31;
  const int ty = threadIdx.x >> 5;
  const int x = blockIdx.x * 32 + tx;
#pragma unroll
  for (int j = 0; j < 4; ++j)
    t[ty + j * 8][tx] = s[(size_t)(blockIdx.y * 32 + ty + j * 8) * Cn + x];
  __syncthreads();
  const int xo = blockIdx.y * 32 + tx;
#pragma unroll
  for (int j = 0; j < 4; ++j)
    d[(size_t)(blockIdx.x * 32 + ty + j * 8) * R + xo] = f2bf(t[tx][ty + j * 8]);
}

// kv [B*S][256] fp32 cols 128..255  ->  vt [B][128][S] bf16 (V transposed)
__global__ __launch_bounds__(256) void transpose_v(const float* __restrict__ kv,
                                                   u16* __restrict__ vt) {
  __shared__ float t[32][33];
  const int tx = threadIdx.x & 31;
  const int ty = threadIdx.x >> 5;
  const int st = blockIdx.x;
  const int dt = blockIdx.y;
  const int b = blockIdx.z;
#pragma unroll
  for (int j = 0; j < 4; ++j)
    t[ty + j * 8][tx] =
        kv[(size_t)(b * S_SZ + st * 32 + ty + j * 8) * 256 + 128 + dt * 32 + tx];
  __syncthreads();
#pragma unroll
  for (int j = 0; j < 4; ++j)
    vt[(size_t)(b * D_SZ + dt * 32 + ty + j * 8) * S_SZ + st * 32 + tx] =
        f2bf(t[tx][ty + j * 8]);
}

// ---------------------------------------------------------------------------
// fp32 LayerNorm (D=128) + interleaved RoPE, bf16 out (scale folded for q).
// ---------------------------------------------------------------------------
__global__ __launch_bounds__(128) void ln_rope(const float* __restrict__ X,
                                               int xstride, u16* __restrict__ Y,
                                               const float* __restrict__ g,
                                               const float* __restrict__ be,
                                               const float* __restrict__ fc,
                                               const float* __restrict__ fs,
                                               int heads, float oscale) {
  __shared__ float red[4];
  const int row = blockIdx.x;
  const int d = threadIdx.x;
  const int s = (row / heads) % S_SZ;

  const float x = X[(size_t)row * xstride + d];
  float v1 = x, v2 = x * x;
#pragma unroll
  for (int off = 1; off < 64; off <<= 1) {
    v1 += __shfl_xor(v1, off);
    v2 += __shfl_xor(v2, off);
  }
  if ((d & 63) == 0) { red[(d >> 6) * 2] = v1; red[(d >> 6) * 2 + 1] = v2; }
  __syncthreads();
  const float mean = (red[0] + red[2]) * (1.f / 128.f);
  const float var = (red[1] + red[3]) * (1.f / 128.f) - mean * mean;
  const float inv = rsqrtf(var + EPS_LN);
  const float y = (x - mean) * inv * g[d] + be[d];
  const float yp = __shfl_xor(y, 1);
  const float c = fc[(size_t)s * D_SZ + d];
  const float sn = fs[(size_t)s * D_SZ + d];
  const float o = (d & 1) ? (yp * sn + y * c) : (y * c - yp * sn);
  Y[(size_t)row * D_SZ + d] = f2bf(o * oscale);
}

// ---------------------------------------------------------------------------
// Flash MQA attention, 32x32x16 MFMA, swapped QK^T (S^T = K·Q^T), softmax
// fully in-register (exp2 domain; Q pre-scaled by log2e/sqrt(D)).
// KVBLK=32: LDS = 2 x (K 8KB + V^T 8KB) = 32 KB -> 3 blocks/CU.
// K and V^T staged via global_load_lds (pre-swizzled sources, linear LDS),
// double-buffered, one barrier per tile.  Wave w owns q-rows qt*128+w*32..+32.
//   C/D layout: col=lane&31, row=(r&3)+8*(r>>2)+4*(lane>>5)
//   A/B frag: row(col)=lane&31, k=(lane>>5)*8+i
// ---------------------------------------------------------------------------
__global__ __launch_bounds__(256, 3) void attn_mfma32(
    const u16* __restrict__ Qbf, const u16* __restrict__ Kbf,
    const u16* __restrict__ Vt, u16* __restrict__ Obf) {
  // per buffer: K tile 32x256B (8KB) then V^T packed 64 rows x 128B (8KB)
  __shared__ char LB[2][16384];

  const int tid = threadIdx.x;
  const int l = tid & 63;
  const int w = tid >> 6;
  const int l31 = l & 31;
  const int hh = l >> 5;

  const int bid = blockIdx.x;
  const int qt = bid & 15;
  const int h = (bid >> 4) % H_SZ;
  const int b = bid / (16 * H_SZ);

  // ---- Q fragments (B operand): lane holds q-row l31, k = hh*8+i ----
  short8 qf[8];
  {
    const u16* qp =
        Qbf + ((size_t)(b * S_SZ + qt * 128 + w * 32 + l31) * H_SZ + h) * D_SZ +
        hh * 8;
#pragma unroll
    for (int dk = 0; dk < 8; ++dk) qf[dk] = *(const short8*)(qp + dk * 16);
  }

  // ---- staging descriptors: 2 K-chunks + 2 V-chunks of 16B per thread ----
  const char* kSrc[2];
  const char* vSrc[2];
  int kLds[2], vLds[2];
#pragma unroll
  for (int i = 0; i < 2; ++i) {
    const int o = (tid + i * 256) * 16;
    {  // K: 32 rows x 256B; swz bits 4-6 (r&7) + bit7 (r>>3)
      const int r = o >> 8;
      const int cl = (o & 255) ^ ((r & 7) << 4) ^ (((r >> 3) & 1) << 7);
      kSrc[i] = (const char*)Kbf + (size_t)(b * S_SZ + r) * 256 + cl;
      kLds[i] = o;
    }
    {  // V^T packed: row r (0..63) = {d=r | d=r+64}, 32 keys x 2B per half
      const int r = o >> 7;
      const int cl = (o & 127) ^ ((r & 7) << 4);
      const int d = r + ((cl >> 6) << 6);
      vSrc[i] = (const char*)Vt + (size_t)(b * D_SZ + d) * (S_SZ * 2) + (cl & 63);
      vLds[i] = 8192 + o;
    }
  }

  f32x16 oa[4];
#pragma unroll
  for (int db = 0; db < 4; ++db) oa[db] = (f32x16)0.f;
  float m_run = -1e30f, l_run = 0.f;

  const int swzK = ((l31 & 7) << 4) ^ (((l31 >> 3) & 1) << 7);

  // prologue: stage tile 0
#pragma unroll
  for (int i = 0; i < 2; ++i) {
    gload_lds16(kSrc[i], &LB[0][kLds[i]]);
    gload_lds16(vSrc[i], &LB[0][vLds[i]]);
  }

  for (int t = 0; t < S_SZ / 32; ++t) {
    __syncthreads();  // drains vmcnt -> tile t ready; all waves past t-1
    if (t < S_SZ / 32 - 1) {
      const int nb = (t + 1) & 1;
#pragma unroll
      for (int i = 0; i < 2; ++i) {
        gload_lds16(kSrc[i] + (size_t)(t + 1) * 8192, &LB[nb][kLds[i]]);
        gload_lds16(vSrc[i] + (t + 1) * 64, &LB[nb][vLds[i]]);
      }
    }
    const char* Kb = &LB[t & 1][0];
    const char* Vb = &LB[t & 1][8192];

    // ---- QK^T: S^T[key][q] (log2 domain), 32 keys per lane-set ----
    f32x16 s0 = (f32x16)0.f;
    __builtin_amdgcn_s_setprio(1);
#pragma unroll
    for (int dk = 0; dk < 8; ++dk) {
      const short8 a0 = *(const short8*)(Kb + l31 * 256 + ((dk * 32 + hh * 16) ^ swzK));
      s0 = __builtin_amdgcn_mfma_f32_32x32x16_bf16(a0, qf[dk], s0, 0, 0, 0);
    }
    __builtin_amdgcn_s_setprio(0);

    // ---- online softmax (exp2 domain, defer-max THR = 8*log2e) ----
    float pm = s0[0];
#pragma unroll
    for (int r = 1; r < 16; ++r) pm = fmaxf(pm, s0[r]);
    pm = fmaxf(pm, __shfl_xor(pm, 32));
    if (!__all(pm <= m_run + 11.5416f)) {
      const float mnew = fmaxf(m_run, pm);
      const float corr = fexp2(m_run - mnew);
      m_run = mnew;
      l_run *= corr;
#pragma unroll
      for (int r = 0; r < 16; ++r) {
        const float cq = __shfl(corr, (r & 3) + 8 * (r >> 2) + 4 * hh);
#pragma unroll
        for (int db = 0; db < 4; ++db) oa[db][r] *= cq;
      }
    }
    float ps = 0.f;
#pragma unroll
    for (int r = 0; r < 16; ++r) { s0[r] = fexp2(s0[r] - m_run); ps += s0[r]; }
    ps += __shfl_xor(ps, 32);
    l_run += ps;

    // ---- PV: O[q][d] += P[q][key] V[key][d], 2 k-steps of 16 keys ----
#pragma unroll
    for (int ks = 0; ks < 2; ++ks) {
      const int rA = ks * 8;      // own regs: keys ks*16 + {0..3}+4hh
      const int rB = ks * 8 + 4;  // own regs: keys ks*16+8 + {0..3}+4hh
      const unsigned xA0 = pack2(s0[rA + 0], s0[rA + 1]);
      const unsigned xA1 = pack2(s0[rA + 2], s0[rA + 3]);
      const unsigned xB0 = pack2(s0[rB + 0], s0[rB + 1]);
      const unsigned xB1 = pack2(s0[rB + 2], s0[rB + 3]);
      const unsigned pA0 = (unsigned)__shfl_xor((int)xA0, 32);
      const unsigned pA1 = (unsigned)__shfl_xor((int)xA1, 32);
      const unsigned pB0 = (unsigned)__shfl_xor((int)xB0, 32);
      const unsigned pB1 = (unsigned)__shfl_xor((int)xB1, 32);
      u32x4 paw;
      paw[0] = hh ? pB0 : xA0;
      paw[1] = hh ? pB1 : xA1;
      paw[2] = hh ? xB0 : pA0;
      paw[3] = hh ? xB1 : pA1;
      const short8 pa = *(const short8*)&paw;
      __builtin_amdgcn_s_setprio(1);
#pragma unroll
      for (int db = 0; db < 4; ++db) {
        const int d = db * 32 + l31;
        const int r = d & 63;
        const int cl = ks * 32 + hh * 16 + ((d >> 6) << 6);
        const short8 vb = *(const short8*)(Vb + r * 128 + (cl ^ ((r & 7) << 4)));
        oa[db] = __builtin_amdgcn_mfma_f32_32x32x16_bf16(pa, vb, oa[db], 0, 0, 0);
      }
      __builtin_amdgcn_s_setprio(0);
    }
  }

  // ---- epilogue: normalize, store bf16 [B,S,H*D] ----
  const float linv = 1.f / l_run;
#pragma unroll
  for (int r = 0; r < 16; ++r) {
    const int crow = (r & 3) + 8 * (r >> 2) + 4 * hh;
    const float inv = __shfl(linv, crow);
    u16* op = Obf + (size_t)(b * S_SZ + qt * 128 + w * 32 + crow) * (H_SZ * D_SZ) +
              h * D_SZ + l31;
#pragma unroll
    for (int db = 0; db < 4; ++db) op[db * 32] = f2bf(oa[db][r] * inv);
  }
}

// ---------------------------------------------------------------------------
extern "C" void kernel_launch(void* const* d_in, const int* in_sizes, int n_in,
                              void* d_out, int out_size, void* d_ws,
                              size_t ws_size, hipStream_t stream) {
  const float* hidden = (const float*)d_in[0];
  const float* fcos = (const float*)d_in[1];
  const float* fsin = (const float*)d_in[2];
  const float* w_q = (const float*)d_in[3];
  const float* w_k = (const float*)d_in[4];
  const float* w_v = (const float*)d_in[5];
  const float* w_o = (const float*)d_in[6];
  const float* ln_q_w = (const float*)d_in[7];
  const float* ln_q_b = (const float*)d_in[8];
  const float* ln_k_w = (const float*)d_in[9];
  const float* ln_k_b = (const float*)d_in[10];
  float* out = (float*)d_out;

  const int M = B_SZ * S_SZ;  // 4096

  char* ws = (char*)d_ws;
  u16* hid_bf = (u16*)ws;                       // 25165824 B [aliased a_bf]
  u16* wqt = (u16*)(ws + 25165824);             // 18874368 B [reused: w_o^T]
  u16* wkvt = (u16*)(ws + 44040192);            //  1572864 B
  float* kv_buf = (float*)(ws + 45613056);      //  4194304 B
  u16* k_bf = (u16*)(ws + 49807360);            //  1048576 B
  u16* vt_bf = (u16*)(ws + 50855936);           //  1048576 B (V^T [B][128][S])
  u16* q_bf = (u16*)(ws + 51904512);            // 25165824 B
  u16* a_bf = hid_bf;   // attn out reuses hid_bf (dead after kv GEMM)
  float* q_f32 = out;   // fp32 q projection lives in d_out until ln_rope

  conv_bf16<<<(M * DIM_SZ) / 2048, 256, 0, stream>>>(hidden, hid_bf, M * DIM_SZ);
  transpose_bf16<<<dim3(DIM_SZ / 32, DIM_SZ / 32), 256, 0, stream>>>(
      w_q, wqt, DIM_SZ, DIM_SZ);
  transpose_bf16<<<dim3(D_SZ / 32, DIM_SZ / 32), 256, 0, stream>>>(
      w_k, wkvt, DIM_SZ, D_SZ);
  transpose_bf16<<<dim3(D_SZ / 32, DIM_SZ / 32), 256, 0, stream>>>(
      w_v, wkvt + (size_t)D_SZ * DIM_SZ, DIM_SZ, D_SZ);

  gemm_bf16<<<(M / 128) * (DIM_SZ / 128), 256, 0, stream>>>(
      hid_bf, wqt, q_f32, M, DIM_SZ, DIM_SZ);
  gemm_bf16<<<(M / 128) * (256 / 128), 256, 0, stream>>>(hid_bf, wkvt, kv_buf,
                                                         M, 256, DIM_SZ);
  transpose_bf16<<<dim3(DIM_SZ / 32, DIM_SZ / 32), 256, 0, stream>>>(
      w_o, wqt, DIM_SZ, DIM_SZ);

  // q pre-scale folds softmax scale AND log2e (exp2-domain softmax):
  // log2(e)/sqrt(128) = 0.1275174365...
  ln_rope<<<M * H_SZ, 128, 0, stream>>>(q_f32, 128, q_bf, ln_q_w, ln_q_b, fcos,
                                        fsin, H_SZ, 0.12751743559f);
  ln_rope<<<M, 128, 0, stream>>>(kv_buf, 256, k_bf, ln_k_w, ln_k_b, fcos, fsin,
                                 1, 1.0f);
  transpose_v<<<dim3(S_SZ / 32, D_SZ / 32, B_SZ), 256, 0, stream>>>(kv_buf,
                                                                    vt_bf);

  attn_mfma32<<<B_SZ * H_SZ * 16, 256, 0, stream>>>(q_bf, k_bf, vt_bf, a_bf);

  gemm_bf16<<<(M / 128) * (DIM_SZ / 128), 256, 0, stream>>>(a_bf, wqt, out, M,
                                                            DIM_SZ, DIM_SZ);
}

// Round 8
// 435.673 us; speedup vs baseline: 13.3559x; 1.1428x over previous
//
#include <hip/hip_runtime.h>
#include <hip/hip_bf16.h>

#define B_SZ 2
#define S_SZ 2048
#define DIM_SZ 3072
#define H_SZ 24
#define D_SZ 128
#define EPS_LN 1e-6f

typedef __attribute__((ext_vector_type(8))) short short8;
typedef __attribute__((ext_vector_type(4))) float f32x4;
typedef __attribute__((ext_vector_type(16))) float f32x16;
typedef __attribute__((ext_vector_type(4))) unsigned int u32x4;
typedef unsigned short u16;

__device__ __forceinline__ float fexp2(float x) {
  return __builtin_amdgcn_exp2f(x);  // v_exp_f32 (native base-2)
}

__device__ __forceinline__ u16 f2bf(float f) {
  union { float f; unsigned u; } x; x.f = f;
  unsigned r = x.u + 0x7fffu + ((x.u >> 16) & 1u);  // RNE
  return (u16)(r >> 16);
}
__device__ __forceinline__ unsigned pack2(float a, float b) {
  return (unsigned)f2bf(a) | ((unsigned)f2bf(b) << 16);
}
// HW packed fp32->bf16 convert: lo = bf16(a), hi = bf16(b).  1 VALU op vs ~10
// for the manual RNE path (T12 recipe).
__device__ __forceinline__ unsigned cvtpk(float a, float b) {
  unsigned r;
  asm("v_cvt_pk_bf16_f32 %0, %1, %2" : "=v"(r) : "v"(a), "v"(b));
  return r;
}

// async global->LDS, 16B per lane (wave-uniform LDS base + lane*16).
typedef const __attribute__((address_space(1))) void* gas_ptr;
typedef __attribute__((address_space(3))) void* las_ptr;
__device__ __forceinline__ void gload_lds16(const void* g, void* l) {
  __builtin_amdgcn_global_load_lds(
      reinterpret_cast<gas_ptr>(reinterpret_cast<uintptr_t>(g)),
      reinterpret_cast<las_ptr>(reinterpret_cast<uintptr_t>(l)), 16, 0, 0);
}

// ---------------------------------------------------------------------------
// bf16 MFMA GEMM with split C-write: logical C[M,N] = A[M,K] @ Bt[N,K]^T.
// Cols < Nsplit -> C (width Nsplit); cols >= Nsplit -> C2 (width N-Nsplit).
// col0 is block-uniform and Nsplit%128==0, so the branch is block-uniform.
// 128x128 tile, BK=64, pre-swizzled global_load_lds staging (validated).
// ---------------------------------------------------------------------------
__global__ __launch_bounds__(256) void gemm_bf16(const u16* __restrict__ A,
                                                 const u16* __restrict__ Bt,
                                                 float* __restrict__ C,
                                                 float* __restrict__ C2,
                                                 int M, int N, int Nsplit,
                                                 int K) {
  __shared__ u16 As[128 * 64];
  __shared__ u16 Bs[128 * 64];
  char* AsB = (char*)As;
  char* BsB = (char*)Bs;

  const int tid = threadIdx.x;
  const int l = tid & 63;
  const int l15 = l & 15;
  const int lg = l >> 4;
  const int w = tid >> 6;
  const int wr = (w >> 1) * 64;
  const int wc = (w & 1) * 64;

  const int nbx = N >> 7;
  int bid = (int)blockIdx.x;
  const int cpx = (int)gridDim.x >> 3;  // nwg % 8 == 0 (bijective XCD swizzle)
  bid = (bid & 7) * cpx + (bid >> 3);
  const int row0 = (bid / nbx) * 128;
  const int col0 = (bid % nbx) * 128;

  size_t abase[4], bbase[4];
  int ldso[4];
#pragma unroll
  for (int i = 0; i < 4; ++i) {
    const int c = tid + i * 256;
    const int o = c * 16;
    const int r = o >> 7;
    const int sb = (o & 127) ^ ((r & 7) << 4);
    ldso[i] = o;
    abase[i] = (size_t)(row0 + r) * K + (sb >> 1);
    bbase[i] = (size_t)(col0 + r) * K + (sb >> 1);
  }
  const int xr = (l15 & 7) << 4;

  f32x4 acc[4][4];
#pragma unroll
  for (int m = 0; m < 4; ++m)
#pragma unroll
    for (int n = 0; n < 4; ++n) acc[m][n] = (f32x4)0.f;

  for (int k0 = 0; k0 < K; k0 += 64) {
    __syncthreads();
#pragma unroll
    for (int i = 0; i < 4; ++i) gload_lds16(A + abase[i] + k0, AsB + ldso[i]);
#pragma unroll
    for (int i = 0; i < 4; ++i) gload_lds16(Bt + bbase[i] + k0, BsB + ldso[i]);
    __syncthreads();

#pragma unroll
    for (int kk = 0; kk < 2; ++kk) {
      const int kb = kk * 64 + lg * 16;
      short8 a[4], b[4];
#pragma unroll
      for (int m = 0; m < 4; ++m)
        a[m] = *(const short8*)(AsB + (wr + m * 16 + l15) * 128 + (kb ^ xr));
#pragma unroll
      for (int n = 0; n < 4; ++n)
        b[n] = *(const short8*)(BsB + (wc + n * 16 + l15) * 128 + (kb ^ xr));
#pragma unroll
      for (int m = 0; m < 4; ++m)
#pragma unroll
        for (int n = 0; n < 4; ++n)
          acc[m][n] =
              __builtin_amdgcn_mfma_f32_16x16x32_bf16(a[m], b[n], acc[m][n], 0, 0, 0);
    }
  }

  const bool lo = (col0 < Nsplit);
  float* Cw = lo ? C : C2;
  const int cw = lo ? Nsplit : (N - Nsplit);
  const int cb = col0 - (lo ? 0 : Nsplit);
#pragma unroll
  for (int m = 0; m < 4; ++m)
#pragma unroll
    for (int n = 0; n < 4; ++n)
#pragma unroll
      for (int r = 0; r < 4; ++r)
        Cw[(size_t)(row0 + wr + m * 16 + lg * 4 + r) * cw + cb + wc + n * 16 +
           l15] = acc[m][n][r];
}

// ---------------------------------------------------------------------------
// fp32 -> bf16 flat convert
// ---------------------------------------------------------------------------
__global__ __launch_bounds__(256) void conv_bf16(const float* __restrict__ s,
                                                 u16* __restrict__ d, int n) {
  const int i = (blockIdx.x * 256 + threadIdx.x) * 8;
  if (i >= n) return;
  const float4 a = *(const float4*)(s + i);
  const float4 b = *(const float4*)(s + i + 4);
  u32x4 pk;
  pk[0] = pack2(a.x, a.y); pk[1] = pack2(a.z, a.w);
  pk[2] = pack2(b.x, b.y); pk[3] = pack2(b.z, b.w);
  *(u32x4*)(d + i) = pk;
}

// fp32 [R][Cn] -> bf16 [Cn][R] transpose
__global__ __launch_bounds__(256) void transpose_bf16(const float* __restrict__ s,
                                                      u16* __restrict__ d,
                                                      int R, int Cn) {
  __shared__ float t[32][33];
  const int tx = threadIdx.x & 31;
  const int ty = threadIdx.x >> 5;
  const int x = blockIdx.x * 32 + tx;
#pragma unroll
  for (int j = 0; j < 4; ++j)
    t[ty + j * 8][tx] = s[(size_t)(blockIdx.y * 32 + ty + j * 8) * Cn + x];
  __syncthreads();
  const int xo = blockIdx.y * 32 + tx;
#pragma unroll
  for (int j = 0; j < 4; ++j)
    d[(size_t)(blockIdx.x * 32 + ty + j * 8) * R + xo] = f2bf(t[tx][ty + j * 8]);
}

// kv [B*S][256] fp32 cols 128..255  ->  vt [B][128][S] bf16 (V transposed)
__global__ __launch_bounds__(256) void transpose_v(const float* __restrict__ kv,
                                                   u16* __restrict__ vt) {
  __shared__ float t[32][33];
  const int tx = threadIdx.x & 31;
  const int ty = threadIdx.x >> 5;
  const int st = blockIdx.x;
  const int dt = blockIdx.y;
  const int b = blockIdx.z;
#pragma unroll
  for (int j = 0; j < 4; ++j)
    t[ty + j * 8][tx] =
        kv[(size_t)(b * S_SZ + st * 32 + ty + j * 8) * 256 + 128 + dt * 32 + tx];
  __syncthreads();
#pragma unroll
  for (int j = 0; j < 4; ++j)
    vt[(size_t)(b * D_SZ + dt * 32 + ty + j * 8) * S_SZ + st * 32 + tx] =
        f2bf(t[tx][ty + j * 8]);
}

// ---------------------------------------------------------------------------
// fp32 LayerNorm (D=128) + interleaved RoPE, bf16 out (scale folded for q).
// ---------------------------------------------------------------------------
__global__ __launch_bounds__(128) void ln_rope(const float* __restrict__ X,
                                               int xstride, u16* __restrict__ Y,
                                               const float* __restrict__ g,
                                               const float* __restrict__ be,
                                               const float* __restrict__ fc,
                                               const float* __restrict__ fs,
                                               int heads, float oscale) {
  __shared__ float red[4];
  const int row = blockIdx.x;
  const int d = threadIdx.x;
  const int s = (row / heads) % S_SZ;

  const float x = X[(size_t)row * xstride + d];
  float v1 = x, v2 = x * x;
#pragma unroll
  for (int off = 1; off < 64; off <<= 1) {
    v1 += __shfl_xor(v1, off);
    v2 += __shfl_xor(v2, off);
  }
  if ((d & 63) == 0) { red[(d >> 6) * 2] = v1; red[(d >> 6) * 2 + 1] = v2; }
  __syncthreads();
  const float mean = (red[0] + red[2]) * (1.f / 128.f);
  const float var = (red[1] + red[3]) * (1.f / 128.f) - mean * mean;
  const float inv = rsqrtf(var + EPS_LN);
  const float y = (x - mean) * inv * g[d] + be[d];
  const float yp = __shfl_xor(y, 1);
  const float c = fc[(size_t)s * D_SZ + d];
  const float sn = fs[(size_t)s * D_SZ + d];
  const float o = (d & 1) ? (yp * sn + y * c) : (y * c - yp * sn);
  Y[(size_t)row * D_SZ + d] = f2bf(o * oscale);
}

// ---------------------------------------------------------------------------
// Flash MQA attention, 32x32x16 MFMA, swapped QK^T (S^T = K·Q^T), softmax
// fully in-register (exp2 domain; Q pre-scaled by log2e/sqrt(D)).
// KVBLK=32, LDS 32 KB (2x16KB dbuf), 3 blocks/CU.  This round: v_cvt_pk for
// P->bf16 (1 op vs ~10), max3-fused max tree, pairwise psum tree.
// ---------------------------------------------------------------------------
__global__ __launch_bounds__(256, 3) void attn_mfma32(
    const u16* __restrict__ Qbf, const u16* __restrict__ Kbf,
    const u16* __restrict__ Vt, u16* __restrict__ Obf) {
  __shared__ char LB[2][16384];

  const int tid = threadIdx.x;
  const int l = tid & 63;
  const int w = tid >> 6;
  const int l31 = l & 31;
  const int hh = l >> 5;

  const int bid = blockIdx.x;
  const int qt = bid & 15;
  const int h = (bid >> 4) % H_SZ;
  const int b = bid / (16 * H_SZ);

  // ---- Q fragments (B operand): lane holds q-row l31, k = hh*8+i ----
  short8 qf[8];
  {
    const u16* qp =
        Qbf + ((size_t)(b * S_SZ + qt * 128 + w * 32 + l31) * H_SZ + h) * D_SZ +
        hh * 8;
#pragma unroll
    for (int dk = 0; dk < 8; ++dk) qf[dk] = *(const short8*)(qp + dk * 16);
  }

  // ---- staging descriptors: 2 K-chunks + 2 V-chunks of 16B per thread ----
  const char* kSrc[2];
  const char* vSrc[2];
  int kLds[2], vLds[2];
#pragma unroll
  for (int i = 0; i < 2; ++i) {
    const int o = (tid + i * 256) * 16;
    {  // K: 32 rows x 256B; swz bits 4-6 (r&7) + bit7 (r>>3)
      const int r = o >> 8;
      const int cl = (o & 255) ^ ((r & 7) << 4) ^ (((r >> 3) & 1) << 7);
      kSrc[i] = (const char*)Kbf + (size_t)(b * S_SZ + r) * 256 + cl;
      kLds[i] = o;
    }
    {  // V^T packed: row r (0..63) = {d=r | d=r+64}, 32 keys x 2B per half
      const int r = o >> 7;
      const int cl = (o & 127) ^ ((r & 7) << 4);
      const int d = r + ((cl >> 6) << 6);
      vSrc[i] = (const char*)Vt + (size_t)(b * D_SZ + d) * (S_SZ * 2) + (cl & 63);
      vLds[i] = 8192 + o;
    }
  }

  f32x16 oa[4];
#pragma unroll
  for (int db = 0; db < 4; ++db) oa[db] = (f32x16)0.f;
  float m_run = -1e30f, l_run = 0.f;

  const int swzK = ((l31 & 7) << 4) ^ (((l31 >> 3) & 1) << 7);

  // prologue: stage tile 0
#pragma unroll
  for (int i = 0; i < 2; ++i) {
    gload_lds16(kSrc[i], &LB[0][kLds[i]]);
    gload_lds16(vSrc[i], &LB[0][vLds[i]]);
  }

  for (int t = 0; t < S_SZ / 32; ++t) {
    __syncthreads();  // drains vmcnt -> tile t ready; all waves past t-1
    if (t < S_SZ / 32 - 1) {
      const int nb = (t + 1) & 1;
#pragma unroll
      for (int i = 0; i < 2; ++i) {
        gload_lds16(kSrc[i] + (size_t)(t + 1) * 8192, &LB[nb][kLds[i]]);
        gload_lds16(vSrc[i] + (t + 1) * 64, &LB[nb][vLds[i]]);
      }
    }
    const char* Kb = &LB[t & 1][0];
    const char* Vb = &LB[t & 1][8192];

    // ---- QK^T: S^T[key][q] (log2 domain), 32 keys per lane-set ----
    f32x16 s0 = (f32x16)0.f;
    __builtin_amdgcn_s_setprio(1);
#pragma unroll
    for (int dk = 0; dk < 8; ++dk) {
      const short8 a0 = *(const short8*)(Kb + l31 * 256 + ((dk * 32 + hh * 16) ^ swzK));
      s0 = __builtin_amdgcn_mfma_f32_32x32x16_bf16(a0, qf[dk], s0, 0, 0, 0);
    }
    __builtin_amdgcn_s_setprio(0);

    // ---- online softmax (exp2 domain, defer-max THR = 8*log2e) ----
    // max3-fused tree (clang fuses fmaxf(fmaxf(a,b),c) -> v_max3_f32)
    const float t0 = fmaxf(fmaxf(s0[0], s0[1]), s0[2]);
    const float t1 = fmaxf(fmaxf(s0[3], s0[4]), s0[5]);
    const float t2 = fmaxf(fmaxf(s0[6], s0[7]), s0[8]);
    const float t3 = fmaxf(fmaxf(s0[9], s0[10]), s0[11]);
    const float t4 = fmaxf(fmaxf(s0[12], s0[13]), s0[14]);
    float pm = fmaxf(fmaxf(fmaxf(t0, t1), t2), fmaxf(fmaxf(t3, t4), s0[15]));
    pm = fmaxf(pm, __shfl_xor(pm, 32));
    if (!__all(pm <= m_run + 11.5416f)) {
      const float mnew = fmaxf(m_run, pm);
      const float corr = fexp2(m_run - mnew);
      m_run = mnew;
      l_run *= corr;
#pragma unroll
      for (int r = 0; r < 16; ++r) {
        const float cq = __shfl(corr, (r & 3) + 8 * (r >> 2) + 4 * hh);
#pragma unroll
        for (int db = 0; db < 4; ++db) oa[db][r] *= cq;
      }
    }
#pragma unroll
    for (int r = 0; r < 16; ++r) s0[r] = fexp2(s0[r] - m_run);
    // pairwise tree sum (short dep chain)
    const float p0 = (s0[0] + s0[1]) + (s0[2] + s0[3]);
    const float p1 = (s0[4] + s0[5]) + (s0[6] + s0[7]);
    const float p2 = (s0[8] + s0[9]) + (s0[10] + s0[11]);
    const float p3 = (s0[12] + s0[13]) + (s0[14] + s0[15]);
    float ps = (p0 + p1) + (p2 + p3);
    ps += __shfl_xor(ps, 32);
    l_run += ps;

    // ---- PV: O[q][d] += P[q][key] V[key][d], 2 k-steps of 16 keys ----
#pragma unroll
    for (int ks = 0; ks < 2; ++ks) {
      const int rA = ks * 8;      // own regs: keys ks*16 + {0..3}+4hh
      const int rB = ks * 8 + 4;  // own regs: keys ks*16+8 + {0..3}+4hh
      const unsigned xA0 = cvtpk(s0[rA + 0], s0[rA + 1]);
      const unsigned xA1 = cvtpk(s0[rA + 2], s0[rA + 3]);
      const unsigned xB0 = cvtpk(s0[rB + 0], s0[rB + 1]);
      const unsigned xB1 = cvtpk(s0[rB + 2], s0[rB + 3]);
      const unsigned pA0 = (unsigned)__shfl_xor((int)xA0, 32);
      const unsigned pA1 = (unsigned)__shfl_xor((int)xA1, 32);
      const unsigned pB0 = (unsigned)__shfl_xor((int)xB0, 32);
      const unsigned pB1 = (unsigned)__shfl_xor((int)xB1, 32);
      u32x4 paw;
      paw[0] = hh ? pB0 : xA0;
      paw[1] = hh ? pB1 : xA1;
      paw[2] = hh ? xB0 : pA0;
      paw[3] = hh ? xB1 : pA1;
      const short8 pa = *(const short8*)&paw;
      __builtin_amdgcn_s_setprio(1);
#pragma unroll
      for (int db = 0; db < 4; ++db) {
        const int d = db * 32 + l31;
        const int r = d & 63;
        const int cl = ks * 32 + hh * 16 + ((d >> 6) << 6);
        const short8 vb = *(const short8*)(Vb + r * 128 + (cl ^ ((r & 7) << 4)));
        oa[db] = __builtin_amdgcn_mfma_f32_32x32x16_bf16(pa, vb, oa[db], 0, 0, 0);
      }
      __builtin_amdgcn_s_setprio(0);
    }
  }

  // ---- epilogue: normalize, store bf16 [B,S,H*D] ----
  const float linv = 1.f / l_run;
#pragma unroll
  for (int r = 0; r < 16; ++r) {
    const int crow = (r & 3) + 8 * (r >> 2) + 4 * hh;
    const float inv = __shfl(linv, crow);
    u16* op = Obf + (size_t)(b * S_SZ + qt * 128 + w * 32 + crow) * (H_SZ * D_SZ) +
              h * D_SZ + l31;
#pragma unroll
    for (int db = 0; db < 4; ++db) op[db * 32] = f2bf(oa[db][r] * inv);
  }
}

// ---------------------------------------------------------------------------
extern "C" void kernel_launch(void* const* d_in, const int* in_sizes, int n_in,
                              void* d_out, int out_size, void* d_ws,
                              size_t ws_size, hipStream_t stream) {
  const float* hidden = (const float*)d_in[0];
  const float* fcos = (const float*)d_in[1];
  const float* fsin = (const float*)d_in[2];
  const float* w_q = (const float*)d_in[3];
  const float* w_k = (const float*)d_in[4];
  const float* w_v = (const float*)d_in[5];
  const float* w_o = (const float*)d_in[6];
  const float* ln_q_w = (const float*)d_in[7];
  const float* ln_q_b = (const float*)d_in[8];
  const float* ln_k_w = (const float*)d_in[9];
  const float* ln_k_b = (const float*)d_in[10];
  float* out = (float*)d_out;

  const int M = B_SZ * S_SZ;  // 4096

  char* ws = (char*)d_ws;
  u16* hid_bf = (u16*)ws;                       // 25165824 B [aliased a_bf]
  u16* wqt = (u16*)(ws + 25165824);             // 18874368 B [reused: w_o^T]
  u16* wkvt = (u16*)(ws + 44040192);            //  1572864 B (contiguous w/ wqt)
  float* kv_buf = (float*)(ws + 45613056);      //  4194304 B
  u16* k_bf = (u16*)(ws + 49807360);            //  1048576 B
  u16* vt_bf = (u16*)(ws + 50855936);           //  1048576 B (V^T [B][128][S])
  u16* q_bf = (u16*)(ws + 51904512);            // 25165824 B
  u16* a_bf = hid_bf;   // attn out reuses hid_bf (dead after qkv GEMM)
  float* q_f32 = out;   // fp32 q projection lives in d_out until ln_rope

  conv_bf16<<<(M * DIM_SZ) / 2048, 256, 0, stream>>>(hidden, hid_bf, M * DIM_SZ);
  transpose_bf16<<<dim3(DIM_SZ / 32, DIM_SZ / 32), 256, 0, stream>>>(
      w_q, wqt, DIM_SZ, DIM_SZ);
  transpose_bf16<<<dim3(D_SZ / 32, DIM_SZ / 32), 256, 0, stream>>>(
      w_k, wkvt, DIM_SZ, D_SZ);
  transpose_bf16<<<dim3(D_SZ / 32, DIM_SZ / 32), 256, 0, stream>>>(
      w_v, wkvt + (size_t)D_SZ * DIM_SZ, DIM_SZ, D_SZ);

  // fused q+kv projection: Bt = [w_q^T | w_k^T | w_v^T] (contiguous rows),
  // N = 3328; cols < 3072 -> q_f32, cols >= 3072 -> kv_buf.
  gemm_bf16<<<(M / 128) * (3328 / 128), 256, 0, stream>>>(
      hid_bf, wqt, q_f32, kv_buf, M, 3328, DIM_SZ, DIM_SZ);
  transpose_bf16<<<dim3(DIM_SZ / 32, DIM_SZ / 32), 256, 0, stream>>>(
      w_o, wqt, DIM_SZ, DIM_SZ);

  // q pre-scale folds softmax scale AND log2e (exp2-domain softmax):
  // log2(e)/sqrt(128) = 0.1275174365...
  ln_rope<<<M * H_SZ, 128, 0, stream>>>(q_f32, 128, q_bf, ln_q_w, ln_q_b, fcos,
                                        fsin, H_SZ, 0.12751743559f);
  ln_rope<<<M, 128, 0, stream>>>(kv_buf, 256, k_bf, ln_k_w, ln_k_b, fcos, fsin,
                                 1, 1.0f);
  transpose_v<<<dim3(S_SZ / 32, D_SZ / 32, B_SZ), 256, 0, stream>>>(kv_buf,
                                                                    vt_bf);

  attn_mfma32<<<B_SZ * H_SZ * 16, 256, 0, stream>>>(q_bf, k_bf, vt_bf, a_bf);

  gemm_bf16<<<(M / 128) * (DIM_SZ / 128), 256, 0, stream>>>(
      a_bf, wqt, out, out, M, DIM_SZ, DIM_SZ, DIM_SZ);
}

// Round 10
// 379.603 us; speedup vs baseline: 15.3287x; 1.1477x over previous
//
#include <hip/hip_runtime.h>
#include <hip/hip_bf16.h>

#define B_SZ 2
#define S_SZ 2048
#define DIM_SZ 3072
#define H_SZ 24
#define D_SZ 128
#define EPS_LN 1e-6f

typedef __attribute__((ext_vector_type(8))) short short8;
typedef __attribute__((ext_vector_type(4))) float f32x4;
typedef __attribute__((ext_vector_type(16))) float f32x16;
typedef __attribute__((ext_vector_type(4))) unsigned int u32x4;
typedef unsigned short u16;

__device__ __forceinline__ float fexp2(float x) {
  return __builtin_amdgcn_exp2f(x);  // v_exp_f32 (native base-2)
}

__device__ __forceinline__ u16 f2bf(float f) {
  union { float f; unsigned u; } x; x.f = f;
  unsigned r = x.u + 0x7fffu + ((x.u >> 16) & 1u);  // RNE
  return (u16)(r >> 16);
}
__device__ __forceinline__ unsigned pack2(float a, float b) {
  return (unsigned)f2bf(a) | ((unsigned)f2bf(b) << 16);
}
__device__ __forceinline__ unsigned cvtpk(float a, float b) {
  unsigned r;
  asm("v_cvt_pk_bf16_f32 %0, %1, %2" : "=v"(r) : "v"(a), "v"(b));
  return r;
}

// async global->LDS, 16B per lane (wave-uniform LDS base + lane*16).
typedef const __attribute__((address_space(1))) void* gas_ptr;
typedef __attribute__((address_space(3))) void* las_ptr;
__device__ __forceinline__ void gload_lds16(const void* g, void* l) {
  __builtin_amdgcn_global_load_lds(
      reinterpret_cast<gas_ptr>(reinterpret_cast<uintptr_t>(g)),
      reinterpret_cast<las_ptr>(reinterpret_cast<uintptr_t>(l)), 16, 0, 0);
}

#define BAR()                              \
  {                                        \
    __builtin_amdgcn_sched_barrier(0);     \
    __builtin_amdgcn_s_barrier();          \
    __builtin_amdgcn_sched_barrier(0);     \
  }

// ---------------------------------------------------------------------------
// 256x256 deep-pipelined bf16 MFMA GEMM (T2 swizzle + T3/T4 counted-vmcnt
// phases + T5 setprio).  8 waves (2Mx4N), per-wave 128x64 out, BK=64.
// LDS: 2 x (A 32KB + B 32KB) = 128KB.  Per K-tile: 4 phases, each
// {ds_read subtile; s_barrier; MFMA quadrant (16); s_barrier}.  Tile t+2 is
// staged at phase 3 of tile t (after all reads of buf[t&1] consumed), then
// s_waitcnt vmcnt(8) waits ONLY tile t+1's loads (t+2's stay in flight).
// Split C-write: cols < Nsplit -> C, else -> C2 (block-uniform).
// ---------------------------------------------------------------------------
__global__ __launch_bounds__(512, 2) void gemm256(const u16* __restrict__ A,
                                                  const u16* __restrict__ Bt,
                                                  float* __restrict__ C,
                                                  float* __restrict__ C2,
                                                  int M, int N, int Nsplit,
                                                  int K) {
  __shared__ u16 LDSb[2][2][256 * 64];  // [buf][A/B][row*64+k]  128 KB

  const int tid = threadIdx.x;
  const int l15 = tid & 15;
  const int lg = (tid >> 4) & 3;
  const int wv = tid >> 6;   // 0..7
  const int wm = wv >> 2;    // 0..1  (M half)
  const int wn = wv & 3;     // 0..3  (N quarter)

  const int nbx = N >> 8;
  int bid = (int)blockIdx.x;
  const int cpx = (int)gridDim.x >> 3;  // grid % 8 == 0 (bijective XCD swizzle)
  bid = (bid & 7) * cpx + (bid >> 3);
  const int row0 = (bid / nbx) * 256;
  const int col0 = (bid % nbx) * 256;

  // staging: 4 chunks of 16B per thread per matrix; pre-swizzled source so
  // linear gload_lds dest matches the swizzled ds_read (rule #21).
  size_t asrc[4], bsrc[4];
  int loff[4];
#pragma unroll
  for (int j = 0; j < 4; ++j) {
    const int o = (tid + j * 512) * 16;         // [0, 32768)
    const int r = o >> 7;                       // LDS row 0..255
    const int sb = (o & 127) ^ ((r & 7) << 4);  // swizzled byte-in-row
    loff[j] = o;
    asrc[j] = (size_t)(row0 + r) * K + (sb >> 1);
    bsrc[j] = (size_t)(col0 + r) * K + (sb >> 1);
  }
  const int xr = (l15 & 7) << 4;

  f32x4 acc[8][4];
#pragma unroll
  for (int m = 0; m < 8; ++m)
#pragma unroll
    for (int n = 0; n < 4; ++n) acc[m][n] = (f32x4)0.f;

  const int NT = K >> 6;

#define STAGE256(t)                                                         \
  {                                                                         \
    char* abL = (char*)&LDSb[(t) & 1][0][0];                                \
    char* bbL = (char*)&LDSb[(t) & 1][1][0];                                \
    _Pragma("unroll") for (int j = 0; j < 4; ++j)                           \
        gload_lds16(A + asrc[j] + (size_t)(t) * 64, abL + loff[j]);         \
    _Pragma("unroll") for (int j = 0; j < 4; ++j)                           \
        gload_lds16(Bt + bsrc[j] + (size_t)(t) * 64, bbL + loff[j]);        \
  }

  // prologue: tiles 0 and 1 in flight; wait tile 0 (oldest 8), sync.
  STAGE256(0);
  STAGE256(1);
  asm volatile("s_waitcnt vmcnt(8)" ::: "memory");
  BAR();

  short8 af[4][2];  // current M-half fragments
  short8 bf[4][2];  // all 4 N fragments

  for (int t = 0; t < NT; ++t) {
    const char* ab = (const char*)&LDSb[t & 1][0][0];
    const char* bb = (const char*)&LDSb[t & 1][1][0];

    // ---- P0: read A(M-half0) + B(n0,n1); MFMA Q0 = m0-3 x n0-1 ----
#pragma unroll
    for (int m = 0; m < 4; ++m)
#pragma unroll
      for (int kk = 0; kk < 2; ++kk)
        af[m][kk] = *(const short8*)(ab + (wm * 128 + m * 16 + l15) * 128 +
                                     ((kk * 64 + lg * 16) ^ xr));
#pragma unroll
    for (int n = 0; n < 2; ++n)
#pragma unroll
      for (int kk = 0; kk < 2; ++kk)
        bf[n][kk] = *(const short8*)(bb + (wn * 64 + n * 16 + l15) * 128 +
                                     ((kk * 64 + lg * 16) ^ xr));
    BAR();
    __builtin_amdgcn_s_setprio(1);
#pragma unroll
    for (int m = 0; m < 4; ++m)
#pragma unroll
      for (int n = 0; n < 2; ++n)
#pragma unroll
        for (int kk = 0; kk < 2; ++kk)
          acc[m][n] = __builtin_amdgcn_mfma_f32_16x16x32_bf16(
              af[m][kk], bf[n][kk], acc[m][n], 0, 0, 0);
    __builtin_amdgcn_s_setprio(0);
    BAR();

    // ---- P1: read B(n2,n3); MFMA Q1 = m0-3 x n2-3 ----
#pragma unroll
    for (int n = 2; n < 4; ++n)
#pragma unroll
      for (int kk = 0; kk < 2; ++kk)
        bf[n][kk] = *(const short8*)(bb + (wn * 64 + n * 16 + l15) * 128 +
                                     ((kk * 64 + lg * 16) ^ xr));
    BAR();
    __builtin_amdgcn_s_setprio(1);
#pragma unroll
    for (int m = 0; m < 4; ++m)
#pragma unroll
      for (int n = 2; n < 4; ++n)
#pragma unroll
        for (int kk = 0; kk < 2; ++kk)
          acc[m][n] = __builtin_amdgcn_mfma_f32_16x16x32_bf16(
              af[m][kk], bf[n][kk], acc[m][n], 0, 0, 0);
    __builtin_amdgcn_s_setprio(0);
    BAR();

    // ---- P2: read A(M-half1) (overwrites af); MFMA Q2 = m4-7 x n2-3 ----
#pragma unroll
    for (int m = 0; m < 4; ++m)
#pragma unroll
      for (int kk = 0; kk < 2; ++kk)
        af[m][kk] = *(const short8*)(ab + (wm * 128 + 64 + m * 16 + l15) * 128 +
                                     ((kk * 64 + lg * 16) ^ xr));
    BAR();
    __builtin_amdgcn_s_setprio(1);
#pragma unroll
    for (int m = 0; m < 4; ++m)
#pragma unroll
      for (int n = 2; n < 4; ++n)
#pragma unroll
        for (int kk = 0; kk < 2; ++kk)
          acc[4 + m][n] = __builtin_amdgcn_mfma_f32_16x16x32_bf16(
              af[m][kk], bf[n][kk], acc[4 + m][n], 0, 0, 0);
    __builtin_amdgcn_s_setprio(0);
    BAR();

    // ---- P3: stage tile t+2 (buf[t&1] now dead); MFMA Q3 = m4-7 x n0-1;
    //          counted vmcnt waits only tile t+1's 8 loads ----
    if (t + 2 < NT) STAGE256(t + 2);
    __builtin_amdgcn_s_setprio(1);
#pragma unroll
    for (int m = 0; m < 4; ++m)
#pragma unroll
      for (int n = 0; n < 2; ++n)
#pragma unroll
        for (int kk = 0; kk < 2; ++kk)
          acc[4 + m][n] = __builtin_amdgcn_mfma_f32_16x16x32_bf16(
              af[m][kk], bf[n][kk], acc[4 + m][n], 0, 0, 0);
    __builtin_amdgcn_s_setprio(0);
    if (t + 2 < NT) {
      asm volatile("s_waitcnt vmcnt(8)" ::: "memory");
    } else if (t + 1 < NT) {
      asm volatile("s_waitcnt vmcnt(0)" ::: "memory");
    }
    BAR();
  }

  // ---- epilogue: split fp32 C-write ----
  const bool lo = (col0 < Nsplit);
  float* Cw = lo ? C : C2;
  const int cw = lo ? Nsplit : (N - Nsplit);
  const int cb = col0 - (lo ? 0 : Nsplit);
#pragma unroll
  for (int m = 0; m < 8; ++m)
#pragma unroll
    for (int n = 0; n < 4; ++n)
#pragma unroll
      for (int r = 0; r < 4; ++r)
        Cw[(size_t)(row0 + wm * 128 + m * 16 + lg * 4 + r) * cw + cb +
           wn * 64 + n * 16 + l15] = acc[m][n][r];
#undef STAGE256
}

// ---------------------------------------------------------------------------
// fp32 -> bf16 flat convert
// ---------------------------------------------------------------------------
__global__ __launch_bounds__(256) void conv_bf16(const float* __restrict__ s,
                                                 u16* __restrict__ d, int n) {
  const int i = (blockIdx.x * 256 + threadIdx.x) * 8;
  if (i >= n) return;
  const float4 a = *(const float4*)(s + i);
  const float4 b = *(const float4*)(s + i + 4);
  u32x4 pk;
  pk[0] = pack2(a.x, a.y); pk[1] = pack2(a.z, a.w);
  pk[2] = pack2(b.x, b.y); pk[3] = pack2(b.z, b.w);
  *(u32x4*)(d + i) = pk;
}

// fp32 [R][Cn] -> bf16 [Cn][R] transpose
__global__ __launch_bounds__(256) void transpose_bf16(const float* __restrict__ s,
                                                      u16* __restrict__ d,
                                                      int R, int Cn) {
  __shared__ float t[32][33];
  const int tx = threadIdx.x & 31;
  const int ty = threadIdx.x >> 5;
  const int x = blockIdx.x * 32 + tx;
#pragma unroll
  for (int j = 0; j < 4; ++j)
    t[ty + j * 8][tx] = s[(size_t)(blockIdx.y * 32 + ty + j * 8) * Cn + x];
  __syncthreads();
  const int xo = blockIdx.y * 32 + tx;
#pragma unroll
  for (int j = 0; j < 4; ++j)
    d[(size_t)(blockIdx.x * 32 + ty + j * 8) * R + xo] = f2bf(t[tx][ty + j * 8]);
}

// kv [B*S][256] fp32 cols 128..255  ->  vt [B][128][S] bf16 (V transposed)
__global__ __launch_bounds__(256) void transpose_v(const float* __restrict__ kv,
                                                   u16* __restrict__ vt) {
  __shared__ float t[32][33];
  const int tx = threadIdx.x & 31;
  const int ty = threadIdx.x >> 5;
  const int st = blockIdx.x;
  const int dt = blockIdx.y;
  const int b = blockIdx.z;
#pragma unroll
  for (int j = 0; j < 4; ++j)
    t[ty + j * 8][tx] =
        kv[(size_t)(b * S_SZ + st * 32 + ty + j * 8) * 256 + 128 + dt * 32 + tx];
  __syncthreads();
#pragma unroll
  for (int j = 0; j < 4; ++j)
    vt[(size_t)(b * D_SZ + dt * 32 + ty + j * 8) * S_SZ + st * 32 + tx] =
        f2bf(t[tx][ty + j * 8]);
}

// ---------------------------------------------------------------------------
// fp32 LayerNorm (D=128) + interleaved RoPE, bf16 out (scale folded for q).
// ---------------------------------------------------------------------------
__global__ __launch_bounds__(128) void ln_rope(const float* __restrict__ X,
                                               int xstride, u16* __restrict__ Y,
                                               const float* __restrict__ g,
                                               const float* __restrict__ be,
                                               const float* __restrict__ fc,
                                               const float* __restrict__ fs,
                                               int heads, float oscale) {
  __shared__ float red[4];
  const int row = blockIdx.x;
  const int d = threadIdx.x;
  const int s = (row / heads) % S_SZ;

  const float x = X[(size_t)row * xstride + d];
  float v1 = x, v2 = x * x;
#pragma unroll
  for (int off = 1; off < 64; off <<= 1) {
    v1 += __shfl_xor(v1, off);
    v2 += __shfl_xor(v2, off);
  }
  if ((d & 63) == 0) { red[(d >> 6) * 2] = v1; red[(d >> 6) * 2 + 1] = v2; }
  __syncthreads();
  const float mean = (red[0] + red[2]) * (1.f / 128.f);
  const float var = (red[1] + red[3]) * (1.f / 128.f) - mean * mean;
  const float inv = rsqrtf(var + EPS_LN);
  const float y = (x - mean) * inv * g[d] + be[d];
  const float yp = __shfl_xor(y, 1);
  const float c = fc[(size_t)s * D_SZ + d];
  const float sn = fs[(size_t)s * D_SZ + d];
  const float o = (d & 1) ? (yp * sn + y * c) : (y * c - yp * sn);
  Y[(size_t)row * D_SZ + d] = f2bf(o * oscale);
}

// ---------------------------------------------------------------------------
// Flash MQA attention (unchanged from round 8, validated).
// ---------------------------------------------------------------------------
__global__ __launch_bounds__(256, 3) void attn_mfma32(
    const u16* __restrict__ Qbf, const u16* __restrict__ Kbf,
    const u16* __restrict__ Vt, u16* __restrict__ Obf) {
  __shared__ char LB[2][16384];

  const int tid = threadIdx.x;
  const int l = tid & 63;
  const int w = tid >> 6;
  const int l31 = l & 31;
  const int hh = l >> 5;

  const int bid = blockIdx.x;
  const int qt = bid & 15;
  const int h = (bid >> 4) % H_SZ;
  const int b = bid / (16 * H_SZ);

  short8 qf[8];
  {
    const u16* qp =
        Qbf + ((size_t)(b * S_SZ + qt * 128 + w * 32 + l31) * H_SZ + h) * D_SZ +
        hh * 8;
#pragma unroll
    for (int dk = 0; dk < 8; ++dk) qf[dk] = *(const short8*)(qp + dk * 16);
  }

  const char* kSrc[2];
  const char* vSrc[2];
  int kLds[2], vLds[2];
#pragma unroll
  for (int i = 0; i < 2; ++i) {
    const int o = (tid + i * 256) * 16;
    {
      const int r = o >> 8;
      const int cl = (o & 255) ^ ((r & 7) << 4) ^ (((r >> 3) & 1) << 7);
      kSrc[i] = (const char*)Kbf + (size_t)(b * S_SZ + r) * 256 + cl;
      kLds[i] = o;
    }
    {
      const int r = o >> 7;
      const int cl = (o & 127) ^ ((r & 7) << 4);
      const int d = r + ((cl >> 6) << 6);
      vSrc[i] = (const char*)Vt + (size_t)(b * D_SZ + d) * (S_SZ * 2) + (cl & 63);
      vLds[i] = 8192 + o;
    }
  }

  f32x16 oa[4];
#pragma unroll
  for (int db = 0; db < 4; ++db) oa[db] = (f32x16)0.f;
  float m_run = -1e30f, l_run = 0.f;

  const int swzK = ((l31 & 7) << 4) ^ (((l31 >> 3) & 1) << 7);

#pragma unroll
  for (int i = 0; i < 2; ++i) {
    gload_lds16(kSrc[i], &LB[0][kLds[i]]);
    gload_lds16(vSrc[i], &LB[0][vLds[i]]);
  }

  for (int t = 0; t < S_SZ / 32; ++t) {
    __syncthreads();
    if (t < S_SZ / 32 - 1) {
      const int nb = (t + 1) & 1;
#pragma unroll
      for (int i = 0; i < 2; ++i) {
        gload_lds16(kSrc[i] + (size_t)(t + 1) * 8192, &LB[nb][kLds[i]]);
        gload_lds16(vSrc[i] + (t + 1) * 64, &LB[nb][vLds[i]]);
      }
    }
    const char* Kb = &LB[t & 1][0];
    const char* Vb = &LB[t & 1][8192];

    f32x16 s0 = (f32x16)0.f;
    __builtin_amdgcn_s_setprio(1);
#pragma unroll
    for (int dk = 0; dk < 8; ++dk) {
      const short8 a0 = *(const short8*)(Kb + l31 * 256 + ((dk * 32 + hh * 16) ^ swzK));
      s0 = __builtin_amdgcn_mfma_f32_32x32x16_bf16(a0, qf[dk], s0, 0, 0, 0);
    }
    __builtin_amdgcn_s_setprio(0);

    const float t0 = fmaxf(fmaxf(s0[0], s0[1]), s0[2]);
    const float t1 = fmaxf(fmaxf(s0[3], s0[4]), s0[5]);
    const float t2 = fmaxf(fmaxf(s0[6], s0[7]), s0[8]);
    const float t3 = fmaxf(fmaxf(s0[9], s0[10]), s0[11]);
    const float t4 = fmaxf(fmaxf(s0[12], s0[13]), s0[14]);
    float pm = fmaxf(fmaxf(fmaxf(t0, t1), t2), fmaxf(fmaxf(t3, t4), s0[15]));
    pm = fmaxf(pm, __shfl_xor(pm, 32));
    if (!__all(pm <= m_run + 11.5416f)) {
      const float mnew = fmaxf(m_run, pm);
      const float corr = fexp2(m_run - mnew);
      m_run = mnew;
      l_run *= corr;
#pragma unroll
      for (int r = 0; r < 16; ++r) {
        const float cq = __shfl(corr, (r & 3) + 8 * (r >> 2) + 4 * hh);
#pragma unroll
        for (int db = 0; db < 4; ++db) oa[db][r] *= cq;
      }
    }
#pragma unroll
    for (int r = 0; r < 16; ++r) s0[r] = fexp2(s0[r] - m_run);
    const float p0 = (s0[0] + s0[1]) + (s0[2] + s0[3]);
    const float p1 = (s0[4] + s0[5]) + (s0[6] + s0[7]);
    const float p2 = (s0[8] + s0[9]) + (s0[10] + s0[11]);
    const float p3 = (s0[12] + s0[13]) + (s0[14] + s0[15]);
    float ps = (p0 + p1) + (p2 + p3);
    ps += __shfl_xor(ps, 32);
    l_run += ps;

#pragma unroll
    for (int ks = 0; ks < 2; ++ks) {
      const int rA = ks * 8;
      const int rB = ks * 8 + 4;
      const unsigned xA0 = cvtpk(s0[rA + 0], s0[rA + 1]);
      const unsigned xA1 = cvtpk(s0[rA + 2], s0[rA + 3]);
      const unsigned xB0 = cvtpk(s0[rB + 0], s0[rB + 1]);
      const unsigned xB1 = cvtpk(s0[rB + 2], s0[rB + 3]);
      const unsigned pA0 = (unsigned)__shfl_xor((int)xA0, 32);
      const unsigned pA1 = (unsigned)__shfl_xor((int)xA1, 32);
      const unsigned pB0 = (unsigned)__shfl_xor((int)xB0, 32);
      const unsigned pB1 = (unsigned)__shfl_xor((int)xB1, 32);
      u32x4 paw;
      paw[0] = hh ? pB0 : xA0;
      paw[1] = hh ? pB1 : xA1;
      paw[2] = hh ? xB0 : pA0;
      paw[3] = hh ? xB1 : pA1;
      const short8 pa = *(const short8*)&paw;
      __builtin_amdgcn_s_setprio(1);
#pragma unroll
      for (int db = 0; db < 4; ++db) {
        const int d = db * 32 + l31;
        const int r = d & 63;
        const int cl = ks * 32 + hh * 16 + ((d >> 6) << 6);
        const short8 vb = *(const short8*)(Vb + r * 128 + (cl ^ ((r & 7) << 4)));
        oa[db] = __builtin_amdgcn_mfma_f32_32x32x16_bf16(pa, vb, oa[db], 0, 0, 0);
      }
      __builtin_amdgcn_s_setprio(0);
    }
  }

  const float linv = 1.f / l_run;
#pragma unroll
  for (int r = 0; r < 16; ++r) {
    const int crow = (r & 3) + 8 * (r >> 2) + 4 * hh;
    const float inv = __shfl(linv, crow);
    u16* op = Obf + (size_t)(b * S_SZ + qt * 128 + w * 32 + crow) * (H_SZ * D_SZ) +
              h * D_SZ + l31;
#pragma unroll
    for (int db = 0; db < 4; ++db) op[db * 32] = f2bf(oa[db][r] * inv);
  }
}

// ---------------------------------------------------------------------------
extern "C" void kernel_launch(void* const* d_in, const int* in_sizes, int n_in,
                              void* d_out, int out_size, void* d_ws,
                              size_t ws_size, hipStream_t stream) {
  const float* hidden = (const float*)d_in[0];
  const float* fcos = (const float*)d_in[1];
  const float* fsin = (const float*)d_in[2];
  const float* w_q = (const float*)d_in[3];
  const float* w_k = (const float*)d_in[4];
  const float* w_v = (const float*)d_in[5];
  const float* w_o = (const float*)d_in[6];
  const float* ln_q_w = (const float*)d_in[7];
  const float* ln_q_b = (const float*)d_in[8];
  const float* ln_k_w = (const float*)d_in[9];
  const float* ln_k_b = (const float*)d_in[10];
  float* out = (float*)d_out;

  const int M = B_SZ * S_SZ;  // 4096

  char* ws = (char*)d_ws;
  u16* hid_bf = (u16*)ws;                       // 25165824 B [aliased a_bf]
  u16* wqt = (u16*)(ws + 25165824);             // 18874368 B [reused: w_o^T]
  u16* wkvt = (u16*)(ws + 44040192);            //  1572864 B (contiguous w/ wqt)
  float* kv_buf = (float*)(ws + 45613056);      //  4194304 B
  u16* k_bf = (u16*)(ws + 49807360);            //  1048576 B
  u16* vt_bf = (u16*)(ws + 50855936);           //  1048576 B (V^T [B][128][S])
  u16* q_bf = (u16*)(ws + 51904512);            // 25165824 B
  u16* a_bf = hid_bf;   // attn out reuses hid_bf (dead after qkv GEMM)
  float* q_f32 = out;   // fp32 q projection lives in d_out until ln_rope

  conv_bf16<<<(M * DIM_SZ) / 2048, 256, 0, stream>>>(hidden, hid_bf, M * DIM_SZ);
  transpose_bf16<<<dim3(DIM_SZ / 32, DIM_SZ / 32), 256, 0, stream>>>(
      w_q, wqt, DIM_SZ, DIM_SZ);
  transpose_bf16<<<dim3(D_SZ / 32, DIM_SZ / 32), 256, 0, stream>>>(
      w_k, wkvt, DIM_SZ, D_SZ);
  transpose_bf16<<<dim3(D_SZ / 32, DIM_SZ / 32), 256, 0, stream>>>(
      w_v, wkvt + (size_t)D_SZ * DIM_SZ, DIM_SZ, D_SZ);

  // fused q+kv projection: Bt = [w_q^T | w_k^T | w_v^T], N=3328;
  // cols < 3072 -> q_f32, cols >= 3072 -> kv_buf.  grid 16x13=208 (%8==0).
  gemm256<<<(M / 256) * (3328 / 256), 512, 0, stream>>>(
      hid_bf, wqt, q_f32, kv_buf, M, 3328, DIM_SZ, DIM_SZ);
  transpose_bf16<<<dim3(DIM_SZ / 32, DIM_SZ / 32), 256, 0, stream>>>(
      w_o, wqt, DIM_SZ, DIM_SZ);

  // q pre-scale folds softmax scale AND log2e: log2(e)/sqrt(128)
  ln_rope<<<M * H_SZ, 128, 0, stream>>>(q_f32, 128, q_bf, ln_q_w, ln_q_b, fcos,
                                        fsin, H_SZ, 0.12751743559f);
  ln_rope<<<M, 128, 0, stream>>>(kv_buf, 256, k_bf, ln_k_w, ln_k_b, fcos, fsin,
                                 1, 1.0f);
  transpose_v<<<dim3(S_SZ / 32, D_SZ / 32, B_SZ), 256, 0, stream>>>(kv_buf,
                                                                    vt_bf);

  attn_mfma32<<<B_SZ * H_SZ * 16, 256, 0, stream>>>(q_bf, k_bf, vt_bf, a_bf);

  // output projection: grid 16x12=192 (%8==0), single C target.
  gemm256<<<(M / 256) * (DIM_SZ / 256), 512, 0, stream>>>(
      a_bf, wqt, out, out, M, DIM_SZ, DIM_SZ, DIM_SZ);
}

// Round 12
// 368.479 us; speedup vs baseline: 15.7914x; 1.0302x over previous
//
#include <hip/hip_runtime.h>
#include <hip/hip_bf16.h>

#define B_SZ 2
#define S_SZ 2048
#define DIM_SZ 3072
#define H_SZ 24
#define D_SZ 128
#define EPS_LN 1e-6f

typedef __attribute__((ext_vector_type(8))) short short8;
typedef __attribute__((ext_vector_type(4))) float f32x4;
typedef __attribute__((ext_vector_type(16))) float f32x16;
typedef __attribute__((ext_vector_type(4))) unsigned int u32x4;
typedef unsigned short u16;

__device__ __forceinline__ float fexp2(float x) {
  return __builtin_amdgcn_exp2f(x);  // v_exp_f32 (native base-2)
}

__device__ __forceinline__ u16 f2bf(float f) {
  union { float f; unsigned u; } x; x.f = f;
  unsigned r = x.u + 0x7fffu + ((x.u >> 16) & 1u);  // RNE
  return (u16)(r >> 16);
}
__device__ __forceinline__ unsigned pack2(float a, float b) {
  return (unsigned)f2bf(a) | ((unsigned)f2bf(b) << 16);
}
__device__ __forceinline__ unsigned cvtpk(float a, float b) {
  unsigned r;
  asm("v_cvt_pk_bf16_f32 %0, %1, %2" : "=v"(r) : "v"(a), "v"(b));
  return r;
}

// async global->LDS, 16B per lane (wave-uniform LDS base + lane*16).
typedef const __attribute__((address_space(1))) void* gas_ptr;
typedef __attribute__((address_space(3))) void* las_ptr;
__device__ __forceinline__ void gload_lds16(const void* g, void* l) {
  __builtin_amdgcn_global_load_lds(
      reinterpret_cast<gas_ptr>(reinterpret_cast<uintptr_t>(g)),
      reinterpret_cast<las_ptr>(reinterpret_cast<uintptr_t>(l)), 16, 0, 0);
}

#define BAR()                              \
  {                                        \
    __builtin_amdgcn_sched_barrier(0);     \
    __builtin_amdgcn_s_barrier();          \
    __builtin_amdgcn_sched_barrier(0);     \
  }

// ---------------------------------------------------------------------------
// 256x256 deep-pipelined bf16 MFMA GEMM (validated round-10).  8 waves
// (2Mx4N), per-wave 128x64, BK=64, LDS 128KB, counted vmcnt(8).
// Split C-write: cols < Nsplit -> C, else -> C2 (block-uniform).
// Used for the fused q+kv projection (N=3328 -> 208 blocks).
// ---------------------------------------------------------------------------
__global__ __launch_bounds__(512, 2) void gemm256(const u16* __restrict__ A,
                                                  const u16* __restrict__ Bt,
                                                  float* __restrict__ C,
                                                  float* __restrict__ C2,
                                                  int M, int N, int Nsplit,
                                                  int K) {
  __shared__ u16 LDSb[2][2][256 * 64];  // [buf][A/B][row*64+k]  128 KB

  const int tid = threadIdx.x;
  const int l15 = tid & 15;
  const int lg = (tid >> 4) & 3;
  const int wv = tid >> 6;   // 0..7
  const int wm = wv >> 2;    // 0..1  (M half)
  const int wn = wv & 3;     // 0..3  (N quarter)

  const int nbx = N >> 8;
  int bid = (int)blockIdx.x;
  const int cpx = (int)gridDim.x >> 3;  // grid % 8 == 0 (bijective XCD swizzle)
  bid = (bid & 7) * cpx + (bid >> 3);
  const int row0 = (bid / nbx) * 256;
  const int col0 = (bid % nbx) * 256;

  size_t asrc[4], bsrc[4];
  int loff[4];
#pragma unroll
  for (int j = 0; j < 4; ++j) {
    const int o = (tid + j * 512) * 16;         // [0, 32768)
    const int r = o >> 7;                       // LDS row 0..255
    const int sb = (o & 127) ^ ((r & 7) << 4);  // swizzled byte-in-row
    loff[j] = o;
    asrc[j] = (size_t)(row0 + r) * K + (sb >> 1);
    bsrc[j] = (size_t)(col0 + r) * K + (sb >> 1);
  }
  const int xr = (l15 & 7) << 4;

  f32x4 acc[8][4];
#pragma unroll
  for (int m = 0; m < 8; ++m)
#pragma unroll
    for (int n = 0; n < 4; ++n) acc[m][n] = (f32x4)0.f;

  const int NT = K >> 6;

#define STAGE256(t)                                                         \
  {                                                                         \
    char* abL = (char*)&LDSb[(t) & 1][0][0];                                \
    char* bbL = (char*)&LDSb[(t) & 1][1][0];                                \
    _Pragma("unroll") for (int j = 0; j < 4; ++j)                           \
        gload_lds16(A + asrc[j] + (size_t)(t) * 64, abL + loff[j]);         \
    _Pragma("unroll") for (int j = 0; j < 4; ++j)                           \
        gload_lds16(Bt + bsrc[j] + (size_t)(t) * 64, bbL + loff[j]);        \
  }

  STAGE256(0);
  STAGE256(1);
  asm volatile("s_waitcnt vmcnt(8)" ::: "memory");
  BAR();

  short8 af[4][2];
  short8 bf[4][2];

  for (int t = 0; t < NT; ++t) {
    const char* ab = (const char*)&LDSb[t & 1][0][0];
    const char* bb = (const char*)&LDSb[t & 1][1][0];

    // P0: A(M-half0) + B(n0,n1); MFMA Q0
#pragma unroll
    for (int m = 0; m < 4; ++m)
#pragma unroll
      for (int kk = 0; kk < 2; ++kk)
        af[m][kk] = *(const short8*)(ab + (wm * 128 + m * 16 + l15) * 128 +
                                     ((kk * 64 + lg * 16) ^ xr));
#pragma unroll
    for (int n = 0; n < 2; ++n)
#pragma unroll
      for (int kk = 0; kk < 2; ++kk)
        bf[n][kk] = *(const short8*)(bb + (wn * 64 + n * 16 + l15) * 128 +
                                     ((kk * 64 + lg * 16) ^ xr));
    BAR();
    __builtin_amdgcn_s_setprio(1);
#pragma unroll
    for (int m = 0; m < 4; ++m)
#pragma unroll
      for (int n = 0; n < 2; ++n)
#pragma unroll
        for (int kk = 0; kk < 2; ++kk)
          acc[m][n] = __builtin_amdgcn_mfma_f32_16x16x32_bf16(
              af[m][kk], bf[n][kk], acc[m][n], 0, 0, 0);
    __builtin_amdgcn_s_setprio(0);
    BAR();

    // P1: B(n2,n3); MFMA Q1
#pragma unroll
    for (int n = 2; n < 4; ++n)
#pragma unroll
      for (int kk = 0; kk < 2; ++kk)
        bf[n][kk] = *(const short8*)(bb + (wn * 64 + n * 16 + l15) * 128 +
                                     ((kk * 64 + lg * 16) ^ xr));
    BAR();
    __builtin_amdgcn_s_setprio(1);
#pragma unroll
    for (int m = 0; m < 4; ++m)
#pragma unroll
      for (int n = 2; n < 4; ++n)
#pragma unroll
        for (int kk = 0; kk < 2; ++kk)
          acc[m][n] = __builtin_amdgcn_mfma_f32_16x16x32_bf16(
              af[m][kk], bf[n][kk], acc[m][n], 0, 0, 0);
    __builtin_amdgcn_s_setprio(0);
    BAR();

    // P2: A(M-half1); MFMA Q2
#pragma unroll
    for (int m = 0; m < 4; ++m)
#pragma unroll
      for (int kk = 0; kk < 2; ++kk)
        af[m][kk] = *(const short8*)(ab + (wm * 128 + 64 + m * 16 + l15) * 128 +
                                     ((kk * 64 + lg * 16) ^ xr));
    BAR();
    __builtin_amdgcn_s_setprio(1);
#pragma unroll
    for (int m = 0; m < 4; ++m)
#pragma unroll
      for (int n = 2; n < 4; ++n)
#pragma unroll
        for (int kk = 0; kk < 2; ++kk)
          acc[4 + m][n] = __builtin_amdgcn_mfma_f32_16x16x32_bf16(
              af[m][kk], bf[n][kk], acc[4 + m][n], 0, 0, 0);
    __builtin_amdgcn_s_setprio(0);
    BAR();

    // P3: stage t+2; MFMA Q3; counted vmcnt
    if (t + 2 < NT) STAGE256(t + 2);
    __builtin_amdgcn_s_setprio(1);
#pragma unroll
    for (int m = 0; m < 4; ++m)
#pragma unroll
      for (int n = 0; n < 2; ++n)
#pragma unroll
        for (int kk = 0; kk < 2; ++kk)
          acc[4 + m][n] = __builtin_amdgcn_mfma_f32_16x16x32_bf16(
              af[m][kk], bf[n][kk], acc[4 + m][n], 0, 0, 0);
    __builtin_amdgcn_s_setprio(0);
    if (t + 2 < NT) {
      asm volatile("s_waitcnt vmcnt(8)" ::: "memory");
    } else if (t + 1 < NT) {
      asm volatile("s_waitcnt vmcnt(0)" ::: "memory");
    }
    BAR();
  }

  const bool lo = (col0 < Nsplit);
  float* Cw = lo ? C : C2;
  const int cw = lo ? Nsplit : (N - Nsplit);
  const int cb = col0 - (lo ? 0 : Nsplit);
#pragma unroll
  for (int m = 0; m < 8; ++m)
#pragma unroll
    for (int n = 0; n < 4; ++n)
#pragma unroll
      for (int r = 0; r < 4; ++r)
        Cw[(size_t)(row0 + wm * 128 + m * 16 + lg * 4 + r) * cw + cb +
           wn * 64 + n * 16 + l15] = acc[m][n][r];
#undef STAGE256
}

// ---------------------------------------------------------------------------
// 256x192-tile variant of the same 4-phase pipeline, for N=3072 outputs:
// grid = (M/256)x(N/192) = 16x16 = 256 blocks -> 100% CU coverage (the 256^2
// tiling only made 192 blocks = 75%).  Per-wave 128x48 (8x3 frags); B has 3
// chunks -> 7 loads/tile -> counted vmcnt(7).  LDS 112 KB.
// ---------------------------------------------------------------------------
__global__ __launch_bounds__(512, 2) void gemm192(const u16* __restrict__ A,
                                                  const u16* __restrict__ Bt,
                                                  float* __restrict__ C,
                                                  int M, int N, int K) {
  __shared__ u16 LA[2][256 * 64];  // 64 KB
  __shared__ u16 LB[2][192 * 64];  // 48 KB

  const int tid = threadIdx.x;
  const int l15 = tid & 15;
  const int lg = (tid >> 4) & 3;
  const int wv = tid >> 6;
  const int wm = wv >> 2;   // 0..1
  const int wn = wv & 3;    // 0..3 -> 48-col strip

  const int nbx = N / 192;
  int bid = (int)blockIdx.x;
  const int cpx = (int)gridDim.x >> 3;
  bid = (bid & 7) * cpx + (bid >> 3);
  const int row0 = (bid / nbx) * 256;
  const int col0 = (bid % nbx) * 192;

  size_t asrc[4], bsrc[3];
  int aoff[4], boff[3];
#pragma unroll
  for (int j = 0; j < 4; ++j) {
    const int o = (tid + j * 512) * 16;  // [0, 32768)
    const int r = o >> 7;
    const int sb = (o & 127) ^ ((r & 7) << 4);
    aoff[j] = o;
    asrc[j] = (size_t)(row0 + r) * K + (sb >> 1);
  }
#pragma unroll
  for (int j = 0; j < 3; ++j) {
    const int o = (tid + j * 512) * 16;  // [0, 24576)
    const int r = o >> 7;                // 0..191
    const int sb = (o & 127) ^ ((r & 7) << 4);
    boff[j] = o;
    bsrc[j] = (size_t)(col0 + r) * K + (sb >> 1);
  }
  const int xr = (l15 & 7) << 4;

  f32x4 acc[8][3];
#pragma unroll
  for (int m = 0; m < 8; ++m)
#pragma unroll
    for (int n = 0; n < 3; ++n) acc[m][n] = (f32x4)0.f;

  const int NT = K >> 6;

#define STAGE192(t)                                                         \
  {                                                                         \
    char* abL = (char*)&LA[(t) & 1][0];                                     \
    char* bbL = (char*)&LB[(t) & 1][0];                                     \
    _Pragma("unroll") for (int j = 0; j < 4; ++j)                           \
        gload_lds16(A + asrc[j] + (size_t)(t) * 64, abL + aoff[j]);         \
    _Pragma("unroll") for (int j = 0; j < 3; ++j)                           \
        gload_lds16(Bt + bsrc[j] + (size_t)(t) * 64, bbL + boff[j]);        \
  }

  STAGE192(0);
  STAGE192(1);
  asm volatile("s_waitcnt vmcnt(7)" ::: "memory");
  BAR();

  short8 af[4][2];
  short8 bf[3][2];

  for (int t = 0; t < NT; ++t) {
    const char* ab = (const char*)&LA[t & 1][0];
    const char* bb = (const char*)&LB[t & 1][0];

    // P0: A(M-half0) + B(n0,n1); MFMA m0-3 x n0-1
#pragma unroll
    for (int m = 0; m < 4; ++m)
#pragma unroll
      for (int kk = 0; kk < 2; ++kk)
        af[m][kk] = *(const short8*)(ab + (wm * 128 + m * 16 + l15) * 128 +
                                     ((kk * 64 + lg * 16) ^ xr));
#pragma unroll
    for (int n = 0; n < 2; ++n)
#pragma unroll
      for (int kk = 0; kk < 2; ++kk)
        bf[n][kk] = *(const short8*)(bb + (wn * 48 + n * 16 + l15) * 128 +
                                     ((kk * 64 + lg * 16) ^ xr));
    BAR();
    __builtin_amdgcn_s_setprio(1);
#pragma unroll
    for (int m = 0; m < 4; ++m)
#pragma unroll
      for (int n = 0; n < 2; ++n)
#pragma unroll
        for (int kk = 0; kk < 2; ++kk)
          acc[m][n] = __builtin_amdgcn_mfma_f32_16x16x32_bf16(
              af[m][kk], bf[n][kk], acc[m][n], 0, 0, 0);
    __builtin_amdgcn_s_setprio(0);
    BAR();

    // P1: B(n2); MFMA m0-3 x n2
#pragma unroll
    for (int kk = 0; kk < 2; ++kk)
      bf[2][kk] = *(const short8*)(bb + (wn * 48 + 32 + l15) * 128 +
                                   ((kk * 64 + lg * 16) ^ xr));
    BAR();
    __builtin_amdgcn_s_setprio(1);
#pragma unroll
    for (int m = 0; m < 4; ++m)
#pragma unroll
      for (int kk = 0; kk < 2; ++kk)
        acc[m][2] = __builtin_amdgcn_mfma_f32_16x16x32_bf16(
            af[m][kk], bf[2][kk], acc[m][2], 0, 0, 0);
    __builtin_amdgcn_s_setprio(0);
    BAR();

    // P2: A(M-half1); MFMA m4-7 x n2
#pragma unroll
    for (int m = 0; m < 4; ++m)
#pragma unroll
      for (int kk = 0; kk < 2; ++kk)
        af[m][kk] = *(const short8*)(ab + (wm * 128 + 64 + m * 16 + l15) * 128 +
                                     ((kk * 64 + lg * 16) ^ xr));
    BAR();
    __builtin_amdgcn_s_setprio(1);
#pragma unroll
    for (int m = 0; m < 4; ++m)
#pragma unroll
      for (int kk = 0; kk < 2; ++kk)
        acc[4 + m][2] = __builtin_amdgcn_mfma_f32_16x16x32_bf16(
            af[m][kk], bf[2][kk], acc[4 + m][2], 0, 0, 0);
    __builtin_amdgcn_s_setprio(0);
    BAR();

    // P3: stage t+2; MFMA m4-7 x n0-1; counted vmcnt(7)
    if (t + 2 < NT) STAGE192(t + 2);
    __builtin_amdgcn_s_setprio(1);
#pragma unroll
    for (int m = 0; m < 4; ++m)
#pragma unroll
      for (int n = 0; n < 2; ++n)
#pragma unroll
        for (int kk = 0; kk < 2; ++kk)
          acc[4 + m][n] = __builtin_amdgcn_mfma_f32_16x16x32_bf16(
              af[m][kk], bf[n][kk], acc[4 + m][n], 0, 0, 0);
    __builtin_amdgcn_s_setprio(0);
    if (t + 2 < NT) {
      asm volatile("s_waitcnt vmcnt(7)" ::: "memory");
    } else if (t + 1 < NT) {
      asm volatile("s_waitcnt vmcnt(0)" ::: "memory");
    }
    BAR();
  }

#pragma unroll
  for (int m = 0; m < 8; ++m)
#pragma unroll
    for (int n = 0; n < 3; ++n)
#pragma unroll
      for (int r = 0; r < 4; ++r)
        C[(size_t)(row0 + wm * 128 + m * 16 + lg * 4 + r) * N + col0 +
          wn * 48 + n * 16 + l15] = acc[m][n][r];
#undef STAGE192
}

// ---------------------------------------------------------------------------
// fp32 -> bf16 flat convert
// ---------------------------------------------------------------------------
__global__ __launch_bounds__(256) void conv_bf16(const float* __restrict__ s,
                                                 u16* __restrict__ d, int n) {
  const int i = (blockIdx.x * 256 + threadIdx.x) * 8;
  if (i >= n) return;
  const float4 a = *(const float4*)(s + i);
  const float4 b = *(const float4*)(s + i + 4);
  u32x4 pk;
  pk[0] = pack2(a.x, a.y); pk[1] = pack2(a.z, a.w);
  pk[2] = pack2(b.x, b.y); pk[3] = pack2(b.z, b.w);
  *(u32x4*)(d + i) = pk;
}

// fp32 [R][Cn] -> bf16 [Cn][R] transpose
__global__ __launch_bounds__(256) void transpose_bf16(const float* __restrict__ s,
                                                      u16* __restrict__ d,
                                                      int R, int Cn) {
  __shared__ float t[32][33];
  const int tx = threadIdx.x & 31;
  const int ty = threadIdx.x >> 5;
  const int x = blockIdx.x * 32 + tx;
#pragma unroll
  for (int j = 0; j < 4; ++j)
    t[ty + j * 8][tx] = s[(size_t)(blockIdx.y * 32 + ty + j * 8) * Cn + x];
  __syncthreads();
  const int xo = blockIdx.y * 32 + tx;
#pragma unroll
  for (int j = 0; j < 4; ++j)
    d[(size_t)(blockIdx.x * 32 + ty + j * 8) * R + xo] = f2bf(t[tx][ty + j * 8]);
}

// kv [B*S][256] fp32 cols 128..255  ->  vt [B][128][S] bf16 (V transposed)
__global__ __launch_bounds__(256) void transpose_v(const float* __restrict__ kv,
                                                   u16* __restrict__ vt) {
  __shared__ float t[32][33];
  const int tx = threadIdx.x & 31;
  const int ty = threadIdx.x >> 5;
  const int st = blockIdx.x;
  const int dt = blockIdx.y;
  const int b = blockIdx.z;
#pragma unroll
  for (int j = 0; j < 4; ++j)
    t[ty + j * 8][tx] =
        kv[(size_t)(b * S_SZ + st * 32 + ty + j * 8) * 256 + 128 + dt * 32 + tx];
  __syncthreads();
#pragma unroll
  for (int j = 0; j < 4; ++j)
    vt[(size_t)(b * D_SZ + dt * 32 + ty + j * 8) * S_SZ + st * 32 + tx] =
        f2bf(t[tx][ty + j * 8]);
}

// ---------------------------------------------------------------------------
// fp32 LayerNorm (D=128) + interleaved RoPE, bf16 out (scale folded for q).
// ---------------------------------------------------------------------------
__global__ __launch_bounds__(128) void ln_rope(const float* __restrict__ X,
                                               int xstride, u16* __restrict__ Y,
                                               const float* __restrict__ g,
                                               const float* __restrict__ be,
                                               const float* __restrict__ fc,
                                               const float* __restrict__ fs,
                                               int heads, float oscale) {
  __shared__ float red[4];
  const int row = blockIdx.x;
  const int d = threadIdx.x;
  const int s = (row / heads) % S_SZ;

  const float x = X[(size_t)row * xstride + d];
  float v1 = x, v2 = x * x;
#pragma unroll
  for (int off = 1; off < 64; off <<= 1) {
    v1 += __shfl_xor(v1, off);
    v2 += __shfl_xor(v2, off);
  }
  if ((d & 63) == 0) { red[(d >> 6) * 2] = v1; red[(d >> 6) * 2 + 1] = v2; }
  __syncthreads();
  const float mean = (red[0] + red[2]) * (1.f / 128.f);
  const float var = (red[1] + red[3]) * (1.f / 128.f) - mean * mean;
  const float inv = rsqrtf(var + EPS_LN);
  const float y = (x - mean) * inv * g[d] + be[d];
  const float yp = __shfl_xor(y, 1);
  const float c = fc[(size_t)s * D_SZ + d];
  const float sn = fs[(size_t)s * D_SZ + d];
  const float o = (d & 1) ? (yp * sn + y * c) : (y * c - yp * sn);
  Y[(size_t)row * D_SZ + d] = f2bf(o * oscale);
}

// ---------------------------------------------------------------------------
// Flash MQA attention (unchanged from round 10, validated).
// ---------------------------------------------------------------------------
__global__ __launch_bounds__(256, 3) void attn_mfma32(
    const u16* __restrict__ Qbf, const u16* __restrict__ Kbf,
    const u16* __restrict__ Vt, u16* __restrict__ Obf) {
  __shared__ char LB[2][16384];

  const int tid = threadIdx.x;
  const int l = tid & 63;
  const int w = tid >> 6;
  const int l31 = l & 31;
  const int hh = l >> 5;

  const int bid = blockIdx.x;
  const int qt = bid & 15;
  const int h = (bid >> 4) % H_SZ;
  const int b = bid / (16 * H_SZ);

  short8 qf[8];
  {
    const u16* qp =
        Qbf + ((size_t)(b * S_SZ + qt * 128 + w * 32 + l31) * H_SZ + h) * D_SZ +
        hh * 8;
#pragma unroll
    for (int dk = 0; dk < 8; ++dk) qf[dk] = *(const short8*)(qp + dk * 16);
  }

  const char* kSrc[2];
  const char* vSrc[2];
  int kLds[2], vLds[2];
#pragma unroll
  for (int i = 0; i < 2; ++i) {
    const int o = (tid + i * 256) * 16;
    {
      const int r = o >> 8;
      const int cl = (o & 255) ^ ((r & 7) << 4) ^ (((r >> 3) & 1) << 7);
      kSrc[i] = (const char*)Kbf + (size_t)(b * S_SZ + r) * 256 + cl;
      kLds[i] = o;
    }
    {
      const int r = o >> 7;
      const int cl = (o & 127) ^ ((r & 7) << 4);
      const int d = r + ((cl >> 6) << 6);
      vSrc[i] = (const char*)Vt + (size_t)(b * D_SZ + d) * (S_SZ * 2) + (cl & 63);
      vLds[i] = 8192 + o;
    }
  }

  f32x16 oa[4];
#pragma unroll
  for (int db = 0; db < 4; ++db) oa[db] = (f32x16)0.f;
  float m_run = -1e30f, l_run = 0.f;

  const int swzK = ((l31 & 7) << 4) ^ (((l31 >> 3) & 1) << 7);

#pragma unroll
  for (int i = 0; i < 2; ++i) {
    gload_lds16(kSrc[i], &LB[0][kLds[i]]);
    gload_lds16(vSrc[i], &LB[0][vLds[i]]);
  }

  for (int t = 0; t < S_SZ / 32; ++t) {
    __syncthreads();
    if (t < S_SZ / 32 - 1) {
      const int nb = (t + 1) & 1;
#pragma unroll
      for (int i = 0; i < 2; ++i) {
        gload_lds16(kSrc[i] + (size_t)(t + 1) * 8192, &LB[nb][kLds[i]]);
        gload_lds16(vSrc[i] + (t + 1) * 64, &LB[nb][vLds[i]]);
      }
    }
    const char* Kb = &LB[t & 1][0];
    const char* Vb = &LB[t & 1][8192];

    f32x16 s0 = (f32x16)0.f;
    __builtin_amdgcn_s_setprio(1);
#pragma unroll
    for (int dk = 0; dk < 8; ++dk) {
      const short8 a0 = *(const short8*)(Kb + l31 * 256 + ((dk * 32 + hh * 16) ^ swzK));
      s0 = __builtin_amdgcn_mfma_f32_32x32x16_bf16(a0, qf[dk], s0, 0, 0, 0);
    }
    __builtin_amdgcn_s_setprio(0);

    const float t0 = fmaxf(fmaxf(s0[0], s0[1]), s0[2]);
    const float t1 = fmaxf(fmaxf(s0[3], s0[4]), s0[5]);
    const float t2 = fmaxf(fmaxf(s0[6], s0[7]), s0[8]);
    const float t3 = fmaxf(fmaxf(s0[9], s0[10]), s0[11]);
    const float t4 = fmaxf(fmaxf(s0[12], s0[13]), s0[14]);
    float pm = fmaxf(fmaxf(fmaxf(t0, t1), t2), fmaxf(fmaxf(t3, t4), s0[15]));
    pm = fmaxf(pm, __shfl_xor(pm, 32));
    if (!__all(pm <= m_run + 11.5416f)) {
      const float mnew = fmaxf(m_run, pm);
      const float corr = fexp2(m_run - mnew);
      m_run = mnew;
      l_run *= corr;
#pragma unroll
      for (int r = 0; r < 16; ++r) {
        const float cq = __shfl(corr, (r & 3) + 8 * (r >> 2) + 4 * hh);
#pragma unroll
        for (int db = 0; db < 4; ++db) oa[db][r] *= cq;
      }
    }
#pragma unroll
    for (int r = 0; r < 16; ++r) s0[r] = fexp2(s0[r] - m_run);
    const float p0 = (s0[0] + s0[1]) + (s0[2] + s0[3]);
    const float p1 = (s0[4] + s0[5]) + (s0[6] + s0[7]);
    const float p2 = (s0[8] + s0[9]) + (s0[10] + s0[11]);
    const float p3 = (s0[12] + s0[13]) + (s0[14] + s0[15]);
    float ps = (p0 + p1) + (p2 + p3);
    ps += __shfl_xor(ps, 32);
    l_run += ps;

#pragma unroll
    for (int ks = 0; ks < 2; ++ks) {
      const int rA = ks * 8;
      const int rB = ks * 8 + 4;
      const unsigned xA0 = cvtpk(s0[rA + 0], s0[rA + 1]);
      const unsigned xA1 = cvtpk(s0[rA + 2], s0[rA + 3]);
      const unsigned xB0 = cvtpk(s0[rB + 0], s0[rB + 1]);
      const unsigned xB1 = cvtpk(s0[rB + 2], s0[rB + 3]);
      const unsigned pA0 = (unsigned)__shfl_xor((int)xA0, 32);
      const unsigned pA1 = (unsigned)__shfl_xor((int)xA1, 32);
      const unsigned pB0 = (unsigned)__shfl_xor((int)xB0, 32);
      const unsigned pB1 = (unsigned)__shfl_xor((int)xB1, 32);
      u32x4 paw;
      paw[0] = hh ? pB0 : xA0;
      paw[1] = hh ? pB1 : xA1;
      paw[2] = hh ? xB0 : pA0;
      paw[3] = hh ? xB1 : pA1;
      const short8 pa = *(const short8*)&paw;
      __builtin_amdgcn_s_setprio(1);
#pragma unroll
      for (int db = 0; db < 4; ++db) {
        const int d = db * 32 + l31;
        const int r = d & 63;
        const int cl = ks * 32 + hh * 16 + ((d >> 6) << 6);
        const short8 vb = *(const short8*)(Vb + r * 128 + (cl ^ ((r & 7) << 4)));
        oa[db] = __builtin_amdgcn_mfma_f32_32x32x16_bf16(pa, vb, oa[db], 0, 0, 0);
      }
      __builtin_amdgcn_s_setprio(0);
    }
  }

  const float linv = 1.f / l_run;
#pragma unroll
  for (int r = 0; r < 16; ++r) {
    const int crow = (r & 3) + 8 * (r >> 2) + 4 * hh;
    const float inv = __shfl(linv, crow);
    u16* op = Obf + (size_t)(b * S_SZ + qt * 128 + w * 32 + crow) * (H_SZ * D_SZ) +
              h * D_SZ + l31;
#pragma unroll
    for (int db = 0; db < 4; ++db) op[db * 32] = f2bf(oa[db][r] * inv);
  }
}

// ---------------------------------------------------------------------------
extern "C" void kernel_launch(void* const* d_in, const int* in_sizes, int n_in,
                              void* d_out, int out_size, void* d_ws,
                              size_t ws_size, hipStream_t stream) {
  const float* hidden = (const float*)d_in[0];
  const float* fcos = (const float*)d_in[1];
  const float* fsin = (const float*)d_in[2];
  const float* w_q = (const float*)d_in[3];
  const float* w_k = (const float*)d_in[4];
  const float* w_v = (const float*)d_in[5];
  const float* w_o = (const float*)d_in[6];
  const float* ln_q_w = (const float*)d_in[7];
  const float* ln_q_b = (const float*)d_in[8];
  const float* ln_k_w = (const float*)d_in[9];
  const float* ln_k_b = (const float*)d_in[10];
  float* out = (float*)d_out;

  const int M = B_SZ * S_SZ;  // 4096

  char* ws = (char*)d_ws;
  u16* hid_bf = (u16*)ws;                       // 25165824 B [aliased a_bf]
  u16* wqt = (u16*)(ws + 25165824);             // 18874368 B [reused: w_o^T]
  u16* wkvt = (u16*)(ws + 44040192);            //  1572864 B (contiguous w/ wqt)
  float* kv_buf = (float*)(ws + 45613056);      //  4194304 B
  u16* k_bf = (u16*)(ws + 49807360);            //  1048576 B
  u16* vt_bf = (u16*)(ws + 50855936);           //  1048576 B (V^T [B][128][S])
  u16* q_bf = (u16*)(ws + 51904512);            // 25165824 B
  u16* a_bf = hid_bf;   // attn out reuses hid_bf (dead after qkv GEMM)
  float* q_f32 = out;   // fp32 q projection lives in d_out until ln_rope

  conv_bf16<<<(M * DIM_SZ) / 2048, 256, 0, stream>>>(hidden, hid_bf, M * DIM_SZ);
  transpose_bf16<<<dim3(DIM_SZ / 32, DIM_SZ / 32), 256, 0, stream>>>(
      w_q, wqt, DIM_SZ, DIM_SZ);
  transpose_bf16<<<dim3(D_SZ / 32, DIM_SZ / 32), 256, 0, stream>>>(
      w_k, wkvt, DIM_SZ, D_SZ);
  transpose_bf16<<<dim3(D_SZ / 32, DIM_SZ / 32), 256, 0, stream>>>(
      w_v, wkvt + (size_t)D_SZ * DIM_SZ, DIM_SZ, D_SZ);

  // fused q+kv projection: Bt = [w_q^T | w_k^T | w_v^T], N=3328;
  // cols < 3072 -> q_f32, cols >= 3072 -> kv_buf.  grid 16x13=208 (%8==0).
  gemm256<<<(M / 256) * (3328 / 256), 512, 0, stream>>>(
      hid_bf, wqt, q_f32, kv_buf, M, 3328, DIM_SZ, DIM_SZ);
  transpose_bf16<<<dim3(DIM_SZ / 32, DIM_SZ / 32), 256, 0, stream>>>(
      w_o, wqt, DIM_SZ, DIM_SZ);

  // q pre-scale folds softmax scale AND log2e: log2(e)/sqrt(128)
  ln_rope<<<M * H_SZ, 128, 0, stream>>>(q_f32, 128, q_bf, ln_q_w, ln_q_b, fcos,
                                        fsin, H_SZ, 0.12751743559f);
  ln_rope<<<M, 128, 0, stream>>>(kv_buf, 256, k_bf, ln_k_w, ln_k_b, fcos, fsin,
                                 1, 1.0f);
  transpose_v<<<dim3(S_SZ / 32, D_SZ / 32, B_SZ), 256, 0, stream>>>(kv_buf,
                                                                    vt_bf);

  attn_mfma32<<<B_SZ * H_SZ * 16, 256, 0, stream>>>(q_bf, k_bf, vt_bf, a_bf);

  // output projection: 256x192 tiles -> grid 16x16 = 256 blocks (100% CU
  // coverage; the 256^2 tiling only made 192 = 75%).
  gemm192<<<(M / 256) * (DIM_SZ / 192), 512, 0, stream>>>(a_bf, wqt, out, M,
                                                          DIM_SZ, DIM_SZ);
}